// Round 6
// baseline (527.841 us; speedup 1.0000x reference)
//
#include <hip/hip_runtime.h>
#include <hip/hip_bf16.h>
#include <math.h>

#define SEQ 2048
#define NH 8
#define DK 64
#define DM 512
#define QSCALE 0.18033688011112042f  // 0.125 * log2(e): exp(x*0.125) == exp2(x*QSCALE)
#define PPAD (SEQ + 128)
#define POFF 64
#define KSTR 72   // K/V LDS row stride (bf16 el): 144B = 16B-aligned
#define PSTR 36   // E1 LDS row stride (f32)
#define ASTR 34   // GEMM LDS row stride (bf16 el): 68B -> 17-bank row offset

typedef unsigned short ushortT;
typedef short s16x8 __attribute__((ext_vector_type(8)));
typedef float f32x4 __attribute__((ext_vector_type(4)));

#define MFMA16 __builtin_amdgcn_mfma_f32_16x16x32_bf16

static __device__ __forceinline__ ushortT f2bf(float x) {
  __hip_bfloat16 h = __float2bfloat16(x);
  ushortT u;
  __builtin_memcpy(&u, &h, 2);
  return u;
}

static __device__ __forceinline__ float fexp2(float x) {
  return __builtin_amdgcn_exp2f(x);
}

static __device__ __forceinline__ s16x8 pack8(const float* p) {
  ushortT u[8];
#pragma unroll
  for (int i = 0; i < 8; ++i) u[i] = f2bf(p[i]);
  s16x8 out;
  __builtin_memcpy(&out, u, 16);
  return out;
}

// pi^-1: j-local column -> A-frag k-slot  (pi(q*8+jj) = jj<4 ? 4q+jj : 16+4q+jj-4)
static __device__ __forceinline__ int pinv(int j) {
  return (j < 16) ? ((j >> 2) * 8 + (j & 3)) : (((j >> 2) - 4) * 8 + 4 + (j & 3));
}

// ---- cast X (4M el) and PE (1M el) to bf16, vectorized x4 ----
__global__ __launch_bounds__(256)
void cast_in(const float* __restrict__ X, const float* __restrict__ PE,
             ushortT* __restrict__ Xb, ushortT* __restrict__ PEb) {
  const size_t i4 = (size_t)blockIdx.x * 256 + threadIdx.x;
  const size_t NX = (size_t)4 * SEQ * DM / 4;
  const float4 v = (i4 < NX) ? *(const float4*)(X + i4 * 4)
                             : *(const float4*)(PE + (i4 - NX) * 4);
  ushortT o[4] = {f2bf(v.x), f2bf(v.y), f2bf(v.z), f2bf(v.w)};
  ushortT* dst = (i4 < NX) ? (Xb + i4 * 4) : (PEb + (i4 - NX) * 4);
  *(ulonglong1*)dst = *(ulonglong1*)o;
}

// ---- transpose 5 weights 512x512 fp32 -> bf16 [n][k], contiguous ----
__global__ __launch_bounds__(256)
void transpose_w(const float* __restrict__ w0, const float* __restrict__ w1,
                 const float* __restrict__ w2, const float* __restrict__ w3,
                 const float* __restrict__ w4, ushortT* __restrict__ out) {
  __shared__ float ts[32][33];
  const int z = blockIdx.z;
  const float* w = (z == 0) ? w0 : (z == 1) ? w1 : (z == 2) ? w2 : (z == 3) ? w3 : w4;
  ushortT* o = out + (size_t)z * DM * DM;
  const int k0 = blockIdx.x * 32, n0 = blockIdx.y * 32;
  const int tx = threadIdx.x, ty = threadIdx.y;
#pragma unroll
  for (int i = 0; i < 4; ++i)
    ts[ty + i * 8][tx] = w[(size_t)(k0 + ty + i * 8) * DM + n0 + tx];
  __syncthreads();
#pragma unroll
  for (int i = 0; i < 4; ++i)
    o[(size_t)(n0 + ty + i * 8) * DM + k0 + tx] = f2bf(ts[tx][ty + i * 8]);
}

// ---- LDS-staged bf16 MFMA GEMM, 128x128 tile, BK=32 (m93 pattern) ----
__global__ __launch_bounds__(256)
void gemm_mfma(const ushortT* __restrict__ A, const ushortT* __restrict__ Bt,
               const float* __restrict__ ubv, const float* __restrict__ vbv,
               ushortT* __restrict__ qu, ushortT* __restrict__ qv,
               ushortT* __restrict__ kb, ushortT* __restrict__ vt,
               float* __restrict__ of, int mode) {
  __shared__ ushortT As[128][ASTR];
  __shared__ ushortT Bs[128][ASTR];
  const int tid = threadIdx.x;
  const int w = tid >> 6, lane = tid & 63;
  const int c = lane & 15, q = lane >> 4;
  const int wm = w >> 1, wn = w & 1;
  const int m0 = blockIdx.x * 128, n0 = blockIdx.y * 128;
  const int lr = tid >> 1, lh = (tid & 1) * 16;  // load row 0..127, k-half

  f32x4 acc[4][4];
#pragma unroll
  for (int mt = 0; mt < 4; ++mt)
#pragma unroll
    for (int nt = 0; nt < 4; ++nt) acc[mt][nt] = (f32x4){0.f, 0.f, 0.f, 0.f};

  const ushortT* Ar = A + (size_t)(m0 + lr) * DM + lh;
  const ushortT* Br = Bt + (size_t)(n0 + lr) * DM + lh;
  uint4 a0 = *(const uint4*)(Ar);
  uint4 a1 = *(const uint4*)(Ar + 8);
  uint4 b0 = *(const uint4*)(Br);
  uint4 b1 = *(const uint4*)(Br + 8);

  for (int k0 = 0; k0 < DM; k0 += 32) {
    __syncthreads();                       // prior compute done reading LDS
    *(uint4*)&As[lr][lh] = a0; *(uint4*)&As[lr][lh + 8] = a1;
    *(uint4*)&Bs[lr][lh] = b0; *(uint4*)&Bs[lr][lh + 8] = b1;
    __syncthreads();                       // staging visible
    if (k0 + 32 < DM) {                    // prefetch next slab (overlaps MFMA)
      a0 = *(const uint4*)(Ar + k0 + 32);
      a1 = *(const uint4*)(Ar + k0 + 40);
      b0 = *(const uint4*)(Br + k0 + 32);
      b1 = *(const uint4*)(Br + k0 + 40);
    }
    s16x8 af[4], bf[4];
#pragma unroll
    for (int mt = 0; mt < 4; ++mt)
      af[mt] = *(const s16x8*)&As[wm * 64 + mt * 16 + c][q * 8];
#pragma unroll
    for (int nt = 0; nt < 4; ++nt)
      bf[nt] = *(const s16x8*)&Bs[wn * 64 + nt * 16 + c][q * 8];
#pragma unroll
    for (int mt = 0; mt < 4; ++mt)
#pragma unroll
      for (int nt = 0; nt < 4; ++nt)
        acc[mt][nt] = MFMA16(af[mt], bf[nt], acc[mt][nt], 0, 0, 0);
  }

#pragma unroll
  for (int mt = 0; mt < 4; ++mt)
#pragma unroll
    for (int nt = 0; nt < 4; ++nt)
#pragma unroll
      for (int r = 0; r < 4; ++r) {
        const int gm = m0 + wm * 64 + mt * 16 + q * 4 + r;
        const int gn = n0 + wn * 64 + nt * 16 + c;
        const float v = acc[mt][nt][r];
        const int bb = gm >> 11, s = gm & (SEQ - 1);
        if (mode == 0) {
          const int z = gn >> 9, gn5 = gn & 511;
          const int h = gn5 >> 6, d = gn5 & 63;
          if (z == 0) {
            const size_t base = (((size_t)bb * NH + h) * SEQ + s) * DK + d;
            qu[base] = f2bf((v + ubv[gn5]) * QSCALE);
            qv[base] = f2bf((v + vbv[gn5]) * QSCALE);
          } else if (z == 1) {
            kb[(((size_t)bb * NH + h) * SEQ + s) * DK + d] = f2bf(v);
          } else {
            const int s_il = (s & ~31) | pinv(s & 31);
            vt[(((size_t)bb * NH + h) * DK + d) * SEQ + s_il] = f2bf(v);
          }
        } else if (mode == 3) {
          const int h = gn >> 6, d = gn & 63;
          qu[((size_t)h * PPAD + POFF + gm) * DK + d] = f2bf(v);
        } else {
          of[(size_t)gm * DM + gn] = v;
        }
      }
}

// ---- band GEMM helper: G = Qrow-block x P[tile*16 .. +15]  (P from L2) ----
static __device__ __forceinline__ f32x4 band_gemm(const ushortT* pb, int tile,
                                                  int c, int q, s16x8 a0, s16x8 a1) {
  const ushortT* pc = pb + (ptrdiff_t)(tile * 16 + c) * DK + q * 8;
  f32x4 G = {0.f, 0.f, 0.f, 0.f};
  G = MFMA16(a0, *(const s16x8*)pc, G, 0, 0, 0);
  G = MFMA16(a1, *(const s16x8*)(pc + 32), G, 0, 0, 0);
  return G;
}

// band GEMM from pre-loaded register fragments
static __device__ __forceinline__ f32x4 band_gemm_r(s16x8 a0, s16x8 a1,
                                                    s16x8 p0, s16x8 p1) {
  f32x4 G = {0.f, 0.f, 0.f, 0.f};
  G = MFMA16(a0, p0, G, 0, 0, 0);
  G = MFMA16(a1, p1, G, 0, 0, 0);
  return G;
}

// shear-transpose band triple -> per-Q-row slots, PAIRED writes (ds_write2).
static __device__ __forceinline__ void write_band2(float (*E)[PSTR], int c, int m_w,
                                                   f32x4 b0, f32x4 b1, f32x4 b2) {
#pragma unroll
  for (int r = 0; r < 4; ++r) {
    const int v = c + m_w + r - 15;
    const bool lo = (v >= 0);
    const int j1 = lo ? v : v + 16;
    const int p = ((j1 >> 2) << 3) | (j1 & 3);
    float* row = &E[m_w + r][p];
    row[0] = lo ? b0[r] : b1[r];
    row[4] = lo ? b1[r] : b2[r];
  }
}

// ---- MFMA flash relative attention: FULLY software-pipelined combine.
// Iteration n: issues K/V LDS reads + S-MFMAs + E1 read for subtile n, but
// executes exp2/pack/PV for subtile n-1 from registers captured last iter
// (S_prev, fE_prev, vb_prev). No same-iteration dependency chain remains on
// the combine; V is register-captured before the chunk barrier so deferral
// legally crosses the staging swap. Phase-B iters (<=2/64, wave-uniform)
// combine synchronously. Band side pipelined as round 3/5 (E1 dbuf).
__global__ __launch_bounds__(256, 3)
void attn_mfma(const ushortT* __restrict__ Qu, const ushortT* __restrict__ Qv,
               const ushortT* __restrict__ Kb, const ushortT* __restrict__ Vt,
               const ushortT* __restrict__ Pp, ushortT* __restrict__ ctxb) {
  const int n = blockIdx.x;
  const int xcd = n & 7, idx = n >> 3;      // XCD x serves h=x (L2 locality)
  const int b = idx >> 5, iblk = idx & 31;
  const int h = xcd, bh = b * 8 + h;
  const int tid = threadIdx.x;
  const int w = tid >> 6, lane = tid & 63;
  const int c = lane & 15, q = lane >> 4;
  const int i0 = iblk * 64;
  const int iw = i0 + w * 16;

  __shared__ ushortT Ks[64][KSTR];
  __shared__ ushortT Vs[64][KSTR];
  __shared__ float E1[4][2][16][PSTR];  // double-buffered pipelined band
  __shared__ float Lb[4][16];

  const ushortT* Qub = Qu + ((size_t)bh * SEQ + iw) * DK;
  const ushortT* Qvb = Qv + ((size_t)bh * SEQ + iw) * DK;
  const ushortT* Kbh = Kb + (size_t)bh * SEQ * DK;
  const ushortT* Vbh = Vt + (size_t)bh * DK * SEQ;
  const ushortT* Ph  = Pp + ((size_t)h * PPAD + POFF) * DK;

  const s16x8 qu0 = *(const s16x8*)(Qub + (size_t)c * DK + q * 8);
  const s16x8 qu1 = *(const s16x8*)(Qub + (size_t)c * DK + 32 + q * 8);
  const s16x8 qv0 = *(const s16x8*)(Qvb + (size_t)c * DK + q * 8);
  const s16x8 qv1 = *(const s16x8*)(Qvb + (size_t)c * DK + 32 + q * 8);
  const s16x8 qw0 = *(const s16x8*)(Qvb + (size_t)(c + 1) * DK + q * 8);
  const s16x8 qw1 = *(const s16x8*)(Qvb + (size_t)(c + 1) * DK + 32 + q * 8);

  // per-slot j-local offsets: pi(q*8+jj)
  int joff[8];
#pragma unroll
  for (int jj = 0; jj < 8; ++jj)
    joff[jj] = (jj < 4) ? (4 * q + jj) : (16 + 4 * q + (jj - 4));

  f32x4 O[4];
#pragma unroll
  for (int r = 0; r < 4; ++r) O[r] = (f32x4){0.f, 0.f, 0.f, 0.f};
  float lrow = 0.f;
  f32x4 e2c = (f32x4){0.f, 0.f, 0.f, 0.f};
  bool hv1 = false, hv2 = false;
  const int jt = iw & ~31;
  const int m_w = q * 4;

  // ---- combine-pipeline state (subtile n-1, all registers) ----
  f32x4 Sp0, Sp1;
  float4 fEpA, fEpB;
  s16x8 vbp0, vbp1, vbp2, vbp3;
  bool have_prev = false;

  // ---- prologue: stage chunk 0 ----
  {
    const ushortT* gk = Kbh;
    uint4 k0v = *(const uint4*)(gk + tid * 8);
    uint4 k1v = *(const uint4*)(gk + 2048 + tid * 8);
    const ushortT* gv = Vbh + (size_t)(tid >> 2) * SEQ + (tid & 3) * 16;
    uint4 v0v = *(const uint4*)gv;
    uint4 v1v = *(const uint4*)(gv + 8);
    *(uint4*)&Ks[tid >> 3][(tid & 7) * 8] = k0v;
    *(uint4*)&Ks[32 + (tid >> 3)][(tid & 7) * 8] = k1v;
    *(uint4*)&Vs[tid >> 2][(tid & 3) * 16] = v0v;
    *(uint4*)&Vs[tid >> 2][(tid & 3) * 16 + 8] = v1v;
  }
  __syncthreads();

  // ---- prologue: band(0) (phase A iff jt > 0; else iter 0 is phase B, sync)
  if (jt > 0) {
    const ushortT* pb1 = Ph + (ptrdiff_t)(0 - iw + SEQ - 16) * DK;
    f32x4 b0 = band_gemm(pb1, 0, c, q, qv0, qv1);
    f32x4 b1 = band_gemm(pb1, 1, c, q, qv0, qv1);
    e2c = band_gemm(pb1, 2, c, q, qv0, qv1);
    hv1 = true;
    write_band2(E1[w][0], c, m_w, b0, b1, e2c);
  }

  // deferred combine for subtile n-1 (inputs are all registers, 1 iter old)
#define DEF_COMBINE()                                                         \
  if (have_prev) {                                                            \
    float pr[8] = {fexp2(Sp0[0] + fEpA.x), fexp2(Sp0[1] + fEpA.y),            \
                   fexp2(Sp0[2] + fEpA.z), fexp2(Sp0[3] + fEpA.w),            \
                   fexp2(Sp1[0] + fEpB.x), fexp2(Sp1[1] + fEpB.y),            \
                   fexp2(Sp1[2] + fEpB.z), fexp2(Sp1[3] + fEpB.w)};           \
    lrow += pr[0] + pr[1] + pr[2] + pr[3] + pr[4] + pr[5] + pr[6] + pr[7];    \
    const s16x8 pa = pack8(pr);                                               \
    O[0] = MFMA16(pa, vbp0, O[0], 0, 0, 0);                                   \
    O[1] = MFMA16(pa, vbp1, O[1], 0, 0, 0);                                   \
    O[2] = MFMA16(pa, vbp2, O[2], 0, 0, 0);                                   \
    O[3] = MFMA16(pa, vbp3, O[3], 0, 0, 0);                                   \
  }

  for (int ch = 0; ch < 32; ++ch) {
    const bool more = (ch + 1) < 32;
    uint4 k0v, k1v, v0v, v1v;
    if (more) {  // prefetch next chunk into registers (overlaps compute)
      const ushortT* gk = Kbh + (size_t)(ch + 1) * 64 * DK;
      k0v = *(const uint4*)(gk + tid * 8);
      k1v = *(const uint4*)(gk + 2048 + tid * 8);
      const ushortT* gv = Vbh + (size_t)(tid >> 2) * SEQ + (ch + 1) * 64 + (tid & 3) * 16;
      v0v = *(const uint4*)gv;
      v1v = *(const uint4*)(gv + 8);
    }
#pragma unroll
    for (int t = 0; t < 2; ++t) {
      const int nn = ch * 2 + t;
      const int j0 = nn * 32;
      const int jl = t * 32;
      const int drel = j0 - iw;
      const bool curB = (j0 >= jt) && (j0 < jt + 64);
      const int j0n = j0 + 32;
      const bool nxtB = (j0n >= jt) && (j0n < jt + 64);
      const bool haveNext = (nn + 1 < 64) && !nxtB;
      const bool nextA = (j0n < jt);

      // ---- unconditional prefetch of next band's P tiles 1,2 ----
      const int dreln = j0n - iw;
      const int row1 = haveNext ? (nextA ? (dreln + SEQ - 16) : (dreln - 17)) : 0;
      const ushortT* pbn = Ph + (ptrdiff_t)row1 * DK;
      const ushortT* pc1 = pbn + (ptrdiff_t)(16 + c) * DK + q * 8;
      const ushortT* pc2 = pbn + (ptrdiff_t)(32 + c) * DK + q * 8;
      const s16x8 p10 = *(const s16x8*)pc1;
      const s16x8 p11 = *(const s16x8*)(pc1 + 32);
      const s16x8 p20 = *(const s16x8*)pc2;
      const s16x8 p21 = *(const s16x8*)(pc2 + 32);

      // ---- this subtile's LDS reads: K frags + V frags (to registers) ----
      const ushortT* ka = &Ks[jl + c][q * 8];
      const s16x8 kf0 = *(const s16x8*)ka;
      const s16x8 kf1 = *(const s16x8*)(ka + 32);
      const ushortT* ka2 = &Ks[jl + 16 + c][q * 8];
      const s16x8 kf2 = *(const s16x8*)ka2;
      const s16x8 kf3 = *(const s16x8*)(ka2 + 32);
      const s16x8 vc0 = *(const s16x8*)&Vs[0 * 16 + c][jl + q * 8];
      const s16x8 vc1 = *(const s16x8*)&Vs[1 * 16 + c][jl + q * 8];
      const s16x8 vc2 = *(const s16x8*)&Vs[2 * 16 + c][jl + q * 8];
      const s16x8 vc3 = *(const s16x8*)&Vs[3 * 16 + c][jl + q * 8];

      // ---- content scores S^T(n): accumulate into T0/T1 ----
      f32x4 T0 = {0.f, 0.f, 0.f, 0.f}, T1 = {0.f, 0.f, 0.f, 0.f};
      T0 = MFMA16(kf0, qu0, T0, 0, 0, 0);
      T0 = MFMA16(kf1, qu1, T0, 0, 0, 0);
      T1 = MFMA16(kf2, qu0, T1, 0, 0, 0);
      T1 = MFMA16(kf3, qu1, T1, 0, 0, 0);

      // ---- E1 read for subtile n (written during iter n-1) ----
      float4 gA = {0.f, 0.f, 0.f, 0.f}, gB = {0.f, 0.f, 0.f, 0.f};
      if (!curB) {
        const float* e1r = &E1[w][nn & 1][c][q * 8];
        gA = *(const float4*)e1r;
        gB = *(const float4*)(e1r + 4);
      }

      // ---- deferred combine for subtile n-1 (register-only inputs) ----
      DEF_COMBINE()
      have_prev = false;

      if (curB) {  // ---- synchronous two-region band + combine (rare) ----
        {
          const ushortT* pb1 = Ph + (ptrdiff_t)(drel + SEQ - 16) * DK;
          f32x4 b0 = band_gemm(pb1, 0, c, q, qv0, qv1);
          f32x4 b1 = band_gemm(pb1, 1, c, q, qv0, qv1);
          f32x4 b2 = band_gemm(pb1, 2, c, q, qv0, qv1);
          write_band2(E1[w][nn & 1], c, m_w, b0, b1, b2);
        }
        {
          // region-2 into the idle double-buffer slot (read back below
          // before the pipeline's later overwrite; per-wave DS is in-order)
          const ushortT* pb2 = Ph + (ptrdiff_t)(drel - 17) * DK;
          f32x4 b0 = band_gemm(pb2, 0, c, q, qw0, qw1);
          f32x4 b1 = band_gemm(pb2, 1, c, q, qw0, qw1);
          f32x4 b2 = band_gemm(pb2, 2, c, q, qw0, qw1);
          write_band2(E1[w][(nn + 1) & 1], c, m_w, b0, b1, b2);
        }
        const float* e1r = &E1[w][nn & 1][c][q * 8];
        const float* e2r = &E1[w][(nn + 1) & 1][c][q * 8];
        float4 aA = *(const float4*)e1r, aB = *(const float4*)(e1r + 4);
        float4 bA = *(const float4*)e2r, bB = *(const float4*)(e2r + 4);
        float f1[8] = {aA.x, aA.y, aA.z, aA.w, aB.x, aB.y, aB.z, aB.w};
        float f2[8] = {bA.x, bA.y, bA.z, bA.w, bB.x, bB.y, bB.z, bB.w};
        float sv[8] = {T0[0], T0[1], T0[2], T0[3], T1[0], T1[1], T1[2], T1[3]};
        float pr[8];
#pragma unroll
        for (int jj = 0; jj < 8; ++jj) {
          const int dlt = drel + joff[jj] - c;
          const float g = (dlt <= 0) ? f1[jj] : ((dlt == 1) ? 0.0f : f2[jj]);
          pr[jj] = fexp2(sv[jj] + g);
        }
        lrow += pr[0] + pr[1] + pr[2] + pr[3] + pr[4] + pr[5] + pr[6] + pr[7];
        const s16x8 pa = pack8(pr);
        O[0] = MFMA16(pa, vc0, O[0], 0, 0, 0);
        O[1] = MFMA16(pa, vc1, O[1], 0, 0, 0);
        O[2] = MFMA16(pa, vc2, O[2], 0, 0, 0);
        O[3] = MFMA16(pa, vc3, O[3], 0, 0, 0);
      } else {     // ---- capture state; combine happens next iteration ----
        Sp0 = T0; Sp1 = T1;
        fEpA = gA; fEpB = gB;
        vbp0 = vc0; vbp1 = vc1; vbp2 = vc2; vbp3 = vc3;
        have_prev = true;
      }

      // ---- pipeline band(nn+1) into E1[(nn+1)&1] with prefetched P regs ---
      if (haveNext) {
        f32x4 b0, b1, b2;
        if (nextA) {
          if (hv1) b0 = e2c;
          else { b0 = band_gemm(pbn, 0, c, q, qv0, qv1); hv1 = true; }
          b1 = band_gemm_r(qv0, qv1, p10, p11);
          b2 = band_gemm_r(qv0, qv1, p20, p21);
        } else {
          if (hv2) b0 = e2c;
          else { b0 = band_gemm(pbn, 0, c, q, qw0, qw1); hv2 = true; }
          b1 = band_gemm_r(qw0, qw1, p10, p11);
          b2 = band_gemm_r(qw0, qw1, p20, p21);
        }
        e2c = b2;
        write_band2(E1[w][(nn + 1) & 1], c, m_w, b0, b1, b2);
      }
    }
    __syncthreads();                     // all waves done reading Ks/Vs
    if (more) {
      *(uint4*)&Ks[tid >> 3][(tid & 7) * 8] = k0v;
      *(uint4*)&Ks[32 + (tid >> 3)][(tid & 7) * 8] = k1v;
      *(uint4*)&Vs[tid >> 2][(tid & 3) * 16] = v0v;
      *(uint4*)&Vs[tid >> 2][(tid & 3) * 16 + 8] = v1v;
    }
    __syncthreads();                     // staging visible
  }

  // ---- flush the last deferred subtile (63, unless it was phase B) ----
  DEF_COMBINE()

  // ---- epilogue (rows exclusive to this wave) ----
  lrow += __shfl_xor(lrow, 16);
  lrow += __shfl_xor(lrow, 32);
  if (q == 0) Lb[w][c] = lrow;
  float inv[4];
#pragma unroll
  for (int r = 0; r < 4; ++r) inv[r] = 1.0f / Lb[w][q * 4 + r];
#pragma unroll
  for (int dt = 0; dt < 4; ++dt)
#pragma unroll
    for (int r = 0; r < 4; ++r) {
      const int i = iw + q * 4 + r;
      ctxb[((size_t)b * SEQ + i) * DM + h * DK + dt * 16 + c] = f2bf(O[dt][r] * inv[r]);
    }
}

extern "C" void kernel_launch(void* const* d_in, const int* in_sizes, int n_in,
                              void* d_out, int out_size, void* d_ws, size_t ws_size,
                              hipStream_t stream) {
  (void)in_sizes; (void)n_in; (void)out_size; (void)ws_size;
  const float* X   = (const float*)d_in[0];
  const float* PE  = (const float*)d_in[1];
  const float* Wq  = (const float*)d_in[2];
  const float* Wk  = (const float*)d_in[3];
  const float* Wv  = (const float*)d_in[4];
  const float* Wo  = (const float*)d_in[5];
  const float* Wp  = (const float*)d_in[6];
  const float* ubv = (const float*)d_in[7];
  const float* vbv = (const float*)d_in[8];

  const size_t NX = (size_t)4 * SEQ * DM;   // 4 Mi
  const size_t NP = (size_t)SEQ * DM;       // 1 Mi
  const size_t NW = (size_t)DM * DM;        // 256 Ki
  ushortT* Xb  = (ushortT*)d_ws;
  ushortT* PEb = Xb + NX;
  ushortT* Wt  = PEb + NP;                  // [Wq^T;Wk^T;Wv^T;Wp^T;Wo^T] bf16
  ushortT* qu  = Wt + 5 * NW;
  ushortT* qv  = qu + NX;
  ushortT* kb  = qv + NX;                   // qw overread from qv lands here: safe
  ushortT* vt  = kb + NX;
  ushortT* pp  = vt + NX;                   // NH*PPAD*DK
  ushortT* ctx = pp + (size_t)NH * PPAD * DK;
  float* outp = (float*)d_out;

  hipLaunchKernelGGL(cast_in, dim3((NX + NP) / 4 / 256), dim3(256), 0, stream, X, PE, Xb, PEb);
  hipLaunchKernelGGL(transpose_w, dim3(16, 16, 5), dim3(32, 8), 0, stream, Wq, Wk, Wv, Wp, Wo, Wt);
  dim3 blk(256);
  hipLaunchKernelGGL(gemm_mfma, dim3(64, 12), blk, 0, stream, Xb, Wt, ubv, vbv,
                     qu, qv, kb, vt, (float*)nullptr, 0);
  hipLaunchKernelGGL(gemm_mfma, dim3(16, 4), blk, 0, stream, PEb, Wt + 3 * NW, ubv, vbv,
                     pp, (ushortT*)nullptr, (ushortT*)nullptr, (ushortT*)nullptr, (float*)nullptr, 3);
  hipLaunchKernelGGL(attn_mfma, dim3(1024), blk, 0, stream, qu, qv, kb, vt, pp, ctx);
  hipLaunchKernelGGL(gemm_mfma, dim3(64, 4), blk, 0, stream, ctx, Wt + 4 * NW, ubv, vbv,
                     (ushortT*)nullptr, (ushortT*)nullptr, (ushortT*)nullptr, (ushortT*)nullptr, outp, 4);
}

// Round 7
// 524.924 us; speedup vs baseline: 1.0056x; 1.0056x over previous
//
#include <hip/hip_runtime.h>
#include <hip/hip_bf16.h>
#include <math.h>

#define SEQ 2048
#define NH 8
#define DK 64
#define DM 512
#define QSCALE 0.18033688011112042f  // 0.125 * log2(e): exp(x*0.125) == exp2(x*QSCALE)
#define PPAD (SEQ + 128)
#define POFF 64
#define KSTR 72   // K/V LDS row stride (bf16 el): 144B = 16B-aligned
#define PSTR 36   // E1 LDS row stride (f32)
#define ASTR 34   // GEMM LDS row stride (bf16 el): 68B -> 17-bank row offset

typedef unsigned short ushortT;
typedef short s16x8 __attribute__((ext_vector_type(8)));
typedef float f32x4 __attribute__((ext_vector_type(4)));

#define MFMA16 __builtin_amdgcn_mfma_f32_16x16x32_bf16

static __device__ __forceinline__ ushortT f2bf(float x) {
  __hip_bfloat16 h = __float2bfloat16(x);
  ushortT u;
  __builtin_memcpy(&u, &h, 2);
  return u;
}

static __device__ __forceinline__ float fexp2(float x) {
  return __builtin_amdgcn_exp2f(x);
}

static __device__ __forceinline__ s16x8 pack8(const float* p) {
  ushortT u[8];
#pragma unroll
  for (int i = 0; i < 8; ++i) u[i] = f2bf(p[i]);
  s16x8 out;
  __builtin_memcpy(&out, u, 16);
  return out;
}

// pi^-1: j-local column -> A-frag k-slot  (pi(q*8+jj) = jj<4 ? 4q+jj : 16+4q+jj-4)
static __device__ __forceinline__ int pinv(int j) {
  return (j < 16) ? ((j >> 2) * 8 + (j & 3)) : (((j >> 2) - 4) * 8 + 4 + (j & 3));
}

// ---- cast X (4M el) and PE (1M el) to bf16, vectorized x4 ----
__global__ __launch_bounds__(256)
void cast_in(const float* __restrict__ X, const float* __restrict__ PE,
             ushortT* __restrict__ Xb, ushortT* __restrict__ PEb) {
  const size_t i4 = (size_t)blockIdx.x * 256 + threadIdx.x;
  const size_t NX = (size_t)4 * SEQ * DM / 4;
  const float4 v = (i4 < NX) ? *(const float4*)(X + i4 * 4)
                             : *(const float4*)(PE + (i4 - NX) * 4);
  ushortT o[4] = {f2bf(v.x), f2bf(v.y), f2bf(v.z), f2bf(v.w)};
  ushortT* dst = (i4 < NX) ? (Xb + i4 * 4) : (PEb + (i4 - NX) * 4);
  *(ulonglong1*)dst = *(ulonglong1*)o;
}

// ---- transpose 5 weights 512x512 fp32 -> bf16 [n][k], contiguous ----
__global__ __launch_bounds__(256)
void transpose_w(const float* __restrict__ w0, const float* __restrict__ w1,
                 const float* __restrict__ w2, const float* __restrict__ w3,
                 const float* __restrict__ w4, ushortT* __restrict__ out) {
  __shared__ float ts[32][33];
  const int z = blockIdx.z;
  const float* w = (z == 0) ? w0 : (z == 1) ? w1 : (z == 2) ? w2 : (z == 3) ? w3 : w4;
  ushortT* o = out + (size_t)z * DM * DM;
  const int k0 = blockIdx.x * 32, n0 = blockIdx.y * 32;
  const int tx = threadIdx.x, ty = threadIdx.y;
#pragma unroll
  for (int i = 0; i < 4; ++i)
    ts[ty + i * 8][tx] = w[(size_t)(k0 + ty + i * 8) * DM + n0 + tx];
  __syncthreads();
#pragma unroll
  for (int i = 0; i < 4; ++i)
    o[(size_t)(n0 + ty + i * 8) * DM + k0 + tx] = f2bf(ts[tx][ty + i * 8]);
}

// ---- LDS-staged bf16 MFMA GEMM, 128x128 tile, BK=32 (m93 pattern) ----
__global__ __launch_bounds__(256)
void gemm_mfma(const ushortT* __restrict__ A, const ushortT* __restrict__ Bt,
               const float* __restrict__ ubv, const float* __restrict__ vbv,
               ushortT* __restrict__ qu, ushortT* __restrict__ qv,
               ushortT* __restrict__ kb, ushortT* __restrict__ vt,
               float* __restrict__ of, int mode) {
  __shared__ ushortT As[128][ASTR];
  __shared__ ushortT Bs[128][ASTR];
  const int tid = threadIdx.x;
  const int w = tid >> 6, lane = tid & 63;
  const int c = lane & 15, q = lane >> 4;
  const int wm = w >> 1, wn = w & 1;
  const int m0 = blockIdx.x * 128, n0 = blockIdx.y * 128;
  const int lr = tid >> 1, lh = (tid & 1) * 16;  // load row 0..127, k-half

  f32x4 acc[4][4];
#pragma unroll
  for (int mt = 0; mt < 4; ++mt)
#pragma unroll
    for (int nt = 0; nt < 4; ++nt) acc[mt][nt] = (f32x4){0.f, 0.f, 0.f, 0.f};

  const ushortT* Ar = A + (size_t)(m0 + lr) * DM + lh;
  const ushortT* Br = Bt + (size_t)(n0 + lr) * DM + lh;
  uint4 a0 = *(const uint4*)(Ar);
  uint4 a1 = *(const uint4*)(Ar + 8);
  uint4 b0 = *(const uint4*)(Br);
  uint4 b1 = *(const uint4*)(Br + 8);

  for (int k0 = 0; k0 < DM; k0 += 32) {
    __syncthreads();                       // prior compute done reading LDS
    *(uint4*)&As[lr][lh] = a0; *(uint4*)&As[lr][lh + 8] = a1;
    *(uint4*)&Bs[lr][lh] = b0; *(uint4*)&Bs[lr][lh + 8] = b1;
    __syncthreads();                       // staging visible
    if (k0 + 32 < DM) {                    // prefetch next slab (overlaps MFMA)
      a0 = *(const uint4*)(Ar + k0 + 32);
      a1 = *(const uint4*)(Ar + k0 + 40);
      b0 = *(const uint4*)(Br + k0 + 32);
      b1 = *(const uint4*)(Br + k0 + 40);
    }
    s16x8 af[4], bf[4];
#pragma unroll
    for (int mt = 0; mt < 4; ++mt)
      af[mt] = *(const s16x8*)&As[wm * 64 + mt * 16 + c][q * 8];
#pragma unroll
    for (int nt = 0; nt < 4; ++nt)
      bf[nt] = *(const s16x8*)&Bs[wn * 64 + nt * 16 + c][q * 8];
#pragma unroll
    for (int mt = 0; mt < 4; ++mt)
#pragma unroll
      for (int nt = 0; nt < 4; ++nt)
        acc[mt][nt] = MFMA16(af[mt], bf[nt], acc[mt][nt], 0, 0, 0);
  }

#pragma unroll
  for (int mt = 0; mt < 4; ++mt)
#pragma unroll
    for (int nt = 0; nt < 4; ++nt)
#pragma unroll
      for (int r = 0; r < 4; ++r) {
        const int gm = m0 + wm * 64 + mt * 16 + q * 4 + r;
        const int gn = n0 + wn * 64 + nt * 16 + c;
        const float v = acc[mt][nt][r];
        const int bb = gm >> 11, s = gm & (SEQ - 1);
        if (mode == 0) {
          const int z = gn >> 9, gn5 = gn & 511;
          const int h = gn5 >> 6, d = gn5 & 63;
          if (z == 0) {
            const size_t base = (((size_t)bb * NH + h) * SEQ + s) * DK + d;
            qu[base] = f2bf((v + ubv[gn5]) * QSCALE);
            qv[base] = f2bf((v + vbv[gn5]) * QSCALE);
          } else if (z == 1) {
            kb[(((size_t)bb * NH + h) * SEQ + s) * DK + d] = f2bf(v);
          } else {
            const int s_il = (s & ~31) | pinv(s & 31);
            vt[(((size_t)bb * NH + h) * DK + d) * SEQ + s_il] = f2bf(v);
          }
        } else if (mode == 3) {
          const int h = gn >> 6, d = gn & 63;
          qu[((size_t)h * PPAD + POFF + gm) * DK + d] = f2bf(v);
        } else {
          of[(size_t)gm * DM + gn] = v;
        }
      }
}

// ---- band GEMM helper: G = Qrow-block x P[tile*16 .. +15]  (P from L2) ----
static __device__ __forceinline__ f32x4 band_gemm(const ushortT* pb, int tile,
                                                  int c, int q, s16x8 a0, s16x8 a1) {
  const ushortT* pc = pb + (ptrdiff_t)(tile * 16 + c) * DK + q * 8;
  f32x4 G = {0.f, 0.f, 0.f, 0.f};
  G = MFMA16(a0, *(const s16x8*)pc, G, 0, 0, 0);
  G = MFMA16(a1, *(const s16x8*)(pc + 32), G, 0, 0, 0);
  return G;
}

// band GEMM from pre-loaded register fragments
static __device__ __forceinline__ f32x4 band_gemm_r(s16x8 a0, s16x8 a1,
                                                    s16x8 p0, s16x8 p1) {
  f32x4 G = {0.f, 0.f, 0.f, 0.f};
  G = MFMA16(a0, p0, G, 0, 0, 0);
  G = MFMA16(a1, p1, G, 0, 0, 0);
  return G;
}

// shear-transpose band triple -> per-Q-row slots, PAIRED writes (ds_write2).
static __device__ __forceinline__ void write_band2(float (*E)[PSTR], int c, int m_w,
                                                   f32x4 b0, f32x4 b1, f32x4 b2) {
#pragma unroll
  for (int r = 0; r < 4; ++r) {
    const int v = c + m_w + r - 15;
    const bool lo = (v >= 0);
    const int j1 = lo ? v : v + 16;
    const int p = ((j1 >> 2) << 3) | (j1 & 3);
    float* row = &E[m_w + r][p];
    row[0] = lo ? b0[r] : b1[r];
    row[4] = lo ? b1[r] : b2[r];
  }
}

// ---- MFMA flash relative attention: FULLY software-pipelined combine
// (round-6 structure, byte-identical) with the register regime FIXED:
// amdgpu_waves_per_eu(3,4) -- max=4 stops the allocator's 6-wave chase that
// spilled ~36 dwords/thread in rounds 4/6; floor VGPR budget 512/4 = 128
// comfortably holds the ~116 live regs of the deferred-combine pipeline.
__global__ __launch_bounds__(256)
__attribute__((amdgpu_waves_per_eu(3, 4)))
void attn_mfma(const ushortT* __restrict__ Qu, const ushortT* __restrict__ Qv,
               const ushortT* __restrict__ Kb, const ushortT* __restrict__ Vt,
               const ushortT* __restrict__ Pp, ushortT* __restrict__ ctxb) {
  const int n = blockIdx.x;
  const int xcd = n & 7, idx = n >> 3;      // XCD x serves h=x (L2 locality)
  const int b = idx >> 5, iblk = idx & 31;
  const int h = xcd, bh = b * 8 + h;
  const int tid = threadIdx.x;
  const int w = tid >> 6, lane = tid & 63;
  const int c = lane & 15, q = lane >> 4;
  const int i0 = iblk * 64;
  const int iw = i0 + w * 16;

  __shared__ ushortT Ks[64][KSTR];
  __shared__ ushortT Vs[64][KSTR];
  __shared__ float E1[4][2][16][PSTR];  // double-buffered pipelined band
  __shared__ float Lb[4][16];

  const ushortT* Qub = Qu + ((size_t)bh * SEQ + iw) * DK;
  const ushortT* Qvb = Qv + ((size_t)bh * SEQ + iw) * DK;
  const ushortT* Kbh = Kb + (size_t)bh * SEQ * DK;
  const ushortT* Vbh = Vt + (size_t)bh * DK * SEQ;
  const ushortT* Ph  = Pp + ((size_t)h * PPAD + POFF) * DK;

  const s16x8 qu0 = *(const s16x8*)(Qub + (size_t)c * DK + q * 8);
  const s16x8 qu1 = *(const s16x8*)(Qub + (size_t)c * DK + 32 + q * 8);
  const s16x8 qv0 = *(const s16x8*)(Qvb + (size_t)c * DK + q * 8);
  const s16x8 qv1 = *(const s16x8*)(Qvb + (size_t)c * DK + 32 + q * 8);
  const s16x8 qw0 = *(const s16x8*)(Qvb + (size_t)(c + 1) * DK + q * 8);
  const s16x8 qw1 = *(const s16x8*)(Qvb + (size_t)(c + 1) * DK + 32 + q * 8);

  // per-slot j-local offsets: pi(q*8+jj)
  int joff[8];
#pragma unroll
  for (int jj = 0; jj < 8; ++jj)
    joff[jj] = (jj < 4) ? (4 * q + jj) : (16 + 4 * q + (jj - 4));

  f32x4 O[4];
#pragma unroll
  for (int r = 0; r < 4; ++r) O[r] = (f32x4){0.f, 0.f, 0.f, 0.f};
  float lrow = 0.f;
  f32x4 e2c = (f32x4){0.f, 0.f, 0.f, 0.f};
  bool hv1 = false, hv2 = false;
  const int jt = iw & ~31;
  const int m_w = q * 4;

  // ---- combine-pipeline state (subtile n-1, all registers) ----
  f32x4 Sp0, Sp1;
  float4 fEpA, fEpB;
  s16x8 vbp0, vbp1, vbp2, vbp3;
  bool have_prev = false;

  // ---- prologue: stage chunk 0 ----
  {
    const ushortT* gk = Kbh;
    uint4 k0v = *(const uint4*)(gk + tid * 8);
    uint4 k1v = *(const uint4*)(gk + 2048 + tid * 8);
    const ushortT* gv = Vbh + (size_t)(tid >> 2) * SEQ + (tid & 3) * 16;
    uint4 v0v = *(const uint4*)gv;
    uint4 v1v = *(const uint4*)(gv + 8);
    *(uint4*)&Ks[tid >> 3][(tid & 7) * 8] = k0v;
    *(uint4*)&Ks[32 + (tid >> 3)][(tid & 7) * 8] = k1v;
    *(uint4*)&Vs[tid >> 2][(tid & 3) * 16] = v0v;
    *(uint4*)&Vs[tid >> 2][(tid & 3) * 16 + 8] = v1v;
  }
  __syncthreads();

  // ---- prologue: band(0) (phase A iff jt > 0; else iter 0 is phase B, sync)
  if (jt > 0) {
    const ushortT* pb1 = Ph + (ptrdiff_t)(0 - iw + SEQ - 16) * DK;
    f32x4 b0 = band_gemm(pb1, 0, c, q, qv0, qv1);
    f32x4 b1 = band_gemm(pb1, 1, c, q, qv0, qv1);
    e2c = band_gemm(pb1, 2, c, q, qv0, qv1);
    hv1 = true;
    write_band2(E1[w][0], c, m_w, b0, b1, e2c);
  }

  // deferred combine for subtile n-1 (inputs are all registers, 1 iter old)
#define DEF_COMBINE()                                                         \
  if (have_prev) {                                                            \
    float pr[8] = {fexp2(Sp0[0] + fEpA.x), fexp2(Sp0[1] + fEpA.y),            \
                   fexp2(Sp0[2] + fEpA.z), fexp2(Sp0[3] + fEpA.w),            \
                   fexp2(Sp1[0] + fEpB.x), fexp2(Sp1[1] + fEpB.y),            \
                   fexp2(Sp1[2] + fEpB.z), fexp2(Sp1[3] + fEpB.w)};           \
    lrow += pr[0] + pr[1] + pr[2] + pr[3] + pr[4] + pr[5] + pr[6] + pr[7];    \
    const s16x8 pa = pack8(pr);                                               \
    O[0] = MFMA16(pa, vbp0, O[0], 0, 0, 0);                                   \
    O[1] = MFMA16(pa, vbp1, O[1], 0, 0, 0);                                   \
    O[2] = MFMA16(pa, vbp2, O[2], 0, 0, 0);                                   \
    O[3] = MFMA16(pa, vbp3, O[3], 0, 0, 0);                                   \
  }

  for (int ch = 0; ch < 32; ++ch) {
    const bool more = (ch + 1) < 32;
    uint4 k0v, k1v, v0v, v1v;
    if (more) {  // prefetch next chunk into registers (overlaps compute)
      const ushortT* gk = Kbh + (size_t)(ch + 1) * 64 * DK;
      k0v = *(const uint4*)(gk + tid * 8);
      k1v = *(const uint4*)(gk + 2048 + tid * 8);
      const ushortT* gv = Vbh + (size_t)(tid >> 2) * SEQ + (ch + 1) * 64 + (tid & 3) * 16;
      v0v = *(const uint4*)gv;
      v1v = *(const uint4*)(gv + 8);
    }
#pragma unroll
    for (int t = 0; t < 2; ++t) {
      const int nn = ch * 2 + t;
      const int j0 = nn * 32;
      const int jl = t * 32;
      const int drel = j0 - iw;
      const bool curB = (j0 >= jt) && (j0 < jt + 64);
      const int j0n = j0 + 32;
      const bool nxtB = (j0n >= jt) && (j0n < jt + 64);
      const bool haveNext = (nn + 1 < 64) && !nxtB;
      const bool nextA = (j0n < jt);

      // ---- unconditional prefetch of next band's P tiles 1,2 ----
      const int dreln = j0n - iw;
      const int row1 = haveNext ? (nextA ? (dreln + SEQ - 16) : (dreln - 17)) : 0;
      const ushortT* pbn = Ph + (ptrdiff_t)row1 * DK;
      const ushortT* pc1 = pbn + (ptrdiff_t)(16 + c) * DK + q * 8;
      const ushortT* pc2 = pbn + (ptrdiff_t)(32 + c) * DK + q * 8;
      const s16x8 p10 = *(const s16x8*)pc1;
      const s16x8 p11 = *(const s16x8*)(pc1 + 32);
      const s16x8 p20 = *(const s16x8*)pc2;
      const s16x8 p21 = *(const s16x8*)(pc2 + 32);

      // ---- this subtile's LDS reads: K frags + V frags (to registers) ----
      const ushortT* ka = &Ks[jl + c][q * 8];
      const s16x8 kf0 = *(const s16x8*)ka;
      const s16x8 kf1 = *(const s16x8*)(ka + 32);
      const ushortT* ka2 = &Ks[jl + 16 + c][q * 8];
      const s16x8 kf2 = *(const s16x8*)ka2;
      const s16x8 kf3 = *(const s16x8*)(ka2 + 32);
      const s16x8 vc0 = *(const s16x8*)&Vs[0 * 16 + c][jl + q * 8];
      const s16x8 vc1 = *(const s16x8*)&Vs[1 * 16 + c][jl + q * 8];
      const s16x8 vc2 = *(const s16x8*)&Vs[2 * 16 + c][jl + q * 8];
      const s16x8 vc3 = *(const s16x8*)&Vs[3 * 16 + c][jl + q * 8];

      // ---- content scores S^T(n): accumulate into T0/T1 ----
      f32x4 T0 = {0.f, 0.f, 0.f, 0.f}, T1 = {0.f, 0.f, 0.f, 0.f};
      T0 = MFMA16(kf0, qu0, T0, 0, 0, 0);
      T0 = MFMA16(kf1, qu1, T0, 0, 0, 0);
      T1 = MFMA16(kf2, qu0, T1, 0, 0, 0);
      T1 = MFMA16(kf3, qu1, T1, 0, 0, 0);

      // ---- E1 read for subtile n (written during iter n-1) ----
      float4 gA = {0.f, 0.f, 0.f, 0.f}, gB = {0.f, 0.f, 0.f, 0.f};
      if (!curB) {
        const float* e1r = &E1[w][nn & 1][c][q * 8];
        gA = *(const float4*)e1r;
        gB = *(const float4*)(e1r + 4);
      }

      // ---- deferred combine for subtile n-1 (register-only inputs) ----
      DEF_COMBINE()
      have_prev = false;

      if (curB) {  // ---- synchronous two-region band + combine (rare) ----
        {
          const ushortT* pb1 = Ph + (ptrdiff_t)(drel + SEQ - 16) * DK;
          f32x4 b0 = band_gemm(pb1, 0, c, q, qv0, qv1);
          f32x4 b1 = band_gemm(pb1, 1, c, q, qv0, qv1);
          f32x4 b2 = band_gemm(pb1, 2, c, q, qv0, qv1);
          write_band2(E1[w][nn & 1], c, m_w, b0, b1, b2);
        }
        {
          // region-2 into the idle double-buffer slot (read back below
          // before the pipeline's later overwrite; per-wave DS is in-order)
          const ushortT* pb2 = Ph + (ptrdiff_t)(drel - 17) * DK;
          f32x4 b0 = band_gemm(pb2, 0, c, q, qw0, qw1);
          f32x4 b1 = band_gemm(pb2, 1, c, q, qw0, qw1);
          f32x4 b2 = band_gemm(pb2, 2, c, q, qw0, qw1);
          write_band2(E1[w][(nn + 1) & 1], c, m_w, b0, b1, b2);
        }
        const float* e1r = &E1[w][nn & 1][c][q * 8];
        const float* e2r = &E1[w][(nn + 1) & 1][c][q * 8];
        float4 aA = *(const float4*)e1r, aB = *(const float4*)(e1r + 4);
        float4 bA = *(const float4*)e2r, bB = *(const float4*)(e2r + 4);
        float f1[8] = {aA.x, aA.y, aA.z, aA.w, aB.x, aB.y, aB.z, aB.w};
        float f2[8] = {bA.x, bA.y, bA.z, bA.w, bB.x, bB.y, bB.z, bB.w};
        float sv[8] = {T0[0], T0[1], T0[2], T0[3], T1[0], T1[1], T1[2], T1[3]};
        float pr[8];
#pragma unroll
        for (int jj = 0; jj < 8; ++jj) {
          const int dlt = drel + joff[jj] - c;
          const float g = (dlt <= 0) ? f1[jj] : ((dlt == 1) ? 0.0f : f2[jj]);
          pr[jj] = fexp2(sv[jj] + g);
        }
        lrow += pr[0] + pr[1] + pr[2] + pr[3] + pr[4] + pr[5] + pr[6] + pr[7];
        const s16x8 pa = pack8(pr);
        O[0] = MFMA16(pa, vc0, O[0], 0, 0, 0);
        O[1] = MFMA16(pa, vc1, O[1], 0, 0, 0);
        O[2] = MFMA16(pa, vc2, O[2], 0, 0, 0);
        O[3] = MFMA16(pa, vc3, O[3], 0, 0, 0);
      } else {     // ---- capture state; combine happens next iteration ----
        Sp0 = T0; Sp1 = T1;
        fEpA = gA; fEpB = gB;
        vbp0 = vc0; vbp1 = vc1; vbp2 = vc2; vbp3 = vc3;
        have_prev = true;
      }

      // ---- pipeline band(nn+1) into E1[(nn+1)&1] with prefetched P regs ---
      if (haveNext) {
        f32x4 b0, b1, b2;
        if (nextA) {
          if (hv1) b0 = e2c;
          else { b0 = band_gemm(pbn, 0, c, q, qv0, qv1); hv1 = true; }
          b1 = band_gemm_r(qv0, qv1, p10, p11);
          b2 = band_gemm_r(qv0, qv1, p20, p21);
        } else {
          if (hv2) b0 = e2c;
          else { b0 = band_gemm(pbn, 0, c, q, qw0, qw1); hv2 = true; }
          b1 = band_gemm_r(qw0, qw1, p10, p11);
          b2 = band_gemm_r(qw0, qw1, p20, p21);
        }
        e2c = b2;
        write_band2(E1[w][(nn + 1) & 1], c, m_w, b0, b1, b2);
      }
    }
    __syncthreads();                     // all waves done reading Ks/Vs
    if (more) {
      *(uint4*)&Ks[tid >> 3][(tid & 7) * 8] = k0v;
      *(uint4*)&Ks[32 + (tid >> 3)][(tid & 7) * 8] = k1v;
      *(uint4*)&Vs[tid >> 2][(tid & 3) * 16] = v0v;
      *(uint4*)&Vs[tid >> 2][(tid & 3) * 16 + 8] = v1v;
    }
    __syncthreads();                     // staging visible
  }

  // ---- flush the last deferred subtile (63, unless it was phase B) ----
  DEF_COMBINE()

  // ---- epilogue (rows exclusive to this wave) ----
  lrow += __shfl_xor(lrow, 16);
  lrow += __shfl_xor(lrow, 32);
  if (q == 0) Lb[w][c] = lrow;
  float inv[4];
#pragma unroll
  for (int r = 0; r < 4; ++r) inv[r] = 1.0f / Lb[w][q * 4 + r];
#pragma unroll
  for (int dt = 0; dt < 4; ++dt)
#pragma unroll
    for (int r = 0; r < 4; ++r) {
      const int i = iw + q * 4 + r;
      ctxb[((size_t)b * SEQ + i) * DM + h * DK + dt * 16 + c] = f2bf(O[dt][r] * inv[r]);
    }
}

extern "C" void kernel_launch(void* const* d_in, const int* in_sizes, int n_in,
                              void* d_out, int out_size, void* d_ws, size_t ws_size,
                              hipStream_t stream) {
  (void)in_sizes; (void)n_in; (void)out_size; (void)ws_size;
  const float* X   = (const float*)d_in[0];
  const float* PE  = (const float*)d_in[1];
  const float* Wq  = (const float*)d_in[2];
  const float* Wk  = (const float*)d_in[3];
  const float* Wv  = (const float*)d_in[4];
  const float* Wo  = (const float*)d_in[5];
  const float* Wp  = (const float*)d_in[6];
  const float* ubv = (const float*)d_in[7];
  const float* vbv = (const float*)d_in[8];

  const size_t NX = (size_t)4 * SEQ * DM;   // 4 Mi
  const size_t NP = (size_t)SEQ * DM;       // 1 Mi
  const size_t NW = (size_t)DM * DM;        // 256 Ki
  ushortT* Xb  = (ushortT*)d_ws;
  ushortT* PEb = Xb + NX;
  ushortT* Wt  = PEb + NP;                  // [Wq^T;Wk^T;Wv^T;Wp^T;Wo^T] bf16
  ushortT* qu  = Wt + 5 * NW;
  ushortT* qv  = qu + NX;
  ushortT* kb  = qv + NX;                   // qw overread from qv lands here: safe
  ushortT* vt  = kb + NX;
  ushortT* pp  = vt + NX;                   // NH*PPAD*DK
  ushortT* ctx = pp + (size_t)NH * PPAD * DK;
  float* outp = (float*)d_out;

  hipLaunchKernelGGL(cast_in, dim3((NX + NP) / 4 / 256), dim3(256), 0, stream, X, PE, Xb, PEb);
  hipLaunchKernelGGL(transpose_w, dim3(16, 16, 5), dim3(32, 8), 0, stream, Wq, Wk, Wv, Wp, Wo, Wt);
  dim3 blk(256);
  hipLaunchKernelGGL(gemm_mfma, dim3(64, 12), blk, 0, stream, Xb, Wt, ubv, vbv,
                     qu, qv, kb, vt, (float*)nullptr, 0);
  hipLaunchKernelGGL(gemm_mfma, dim3(16, 4), blk, 0, stream, PEb, Wt + 3 * NW, ubv, vbv,
                     pp, (ushortT*)nullptr, (ushortT*)nullptr, (ushortT*)nullptr, (float*)nullptr, 3);
  hipLaunchKernelGGL(attn_mfma, dim3(1024), blk, 0, stream, qu, qv, kb, vt, pp, ctx);
  hipLaunchKernelGGL(gemm_mfma, dim3(64, 4), blk, 0, stream, ctx, Wt + 4 * NW, ubv, vbv,
                     (ushortT*)nullptr, (ushortT*)nullptr, (ushortT*)nullptr, (ushortT*)nullptr, outp, 4);
}

// Round 8
// 471.646 us; speedup vs baseline: 1.1191x; 1.1130x over previous
//
#include <hip/hip_runtime.h>
#include <hip/hip_bf16.h>
#include <math.h>

#define SEQ 2048
#define NH 8
#define DK 64
#define DM 512
#define QSCALE 0.18033688011112042f  // 0.125 * log2(e): exp(x*0.125) == exp2(x*QSCALE)
#define PPAD (SEQ + 128)
#define POFF 64
#define KSTR 72   // K/V LDS row stride (bf16 el): 144B = 16B-aligned
#define PSTR 36   // E1/E2 LDS row stride (f32)
#define ASTR 34   // GEMM LDS row stride (bf16 el): 68B -> 17-bank row offset

typedef unsigned short ushortT;
typedef short s16x8 __attribute__((ext_vector_type(8)));
typedef float f32x4 __attribute__((ext_vector_type(4)));

#define MFMA16 __builtin_amdgcn_mfma_f32_16x16x32_bf16

static __device__ __forceinline__ ushortT f2bf(float x) {
  __hip_bfloat16 h = __float2bfloat16(x);
  ushortT u;
  __builtin_memcpy(&u, &h, 2);
  return u;
}

static __device__ __forceinline__ float fexp2(float x) {
  return __builtin_amdgcn_exp2f(x);
}

static __device__ __forceinline__ s16x8 pack8(const float* p) {
  ushortT u[8];
#pragma unroll
  for (int i = 0; i < 8; ++i) u[i] = f2bf(p[i]);
  s16x8 out;
  __builtin_memcpy(&out, u, 16);
  return out;
}

// pi^-1: j-local column -> A-frag k-slot  (pi(q*8+jj) = jj<4 ? 4q+jj : 16+4q+jj-4)
static __device__ __forceinline__ int pinv(int j) {
  return (j < 16) ? ((j >> 2) * 8 + (j & 3)) : (((j >> 2) - 4) * 8 + 4 + (j & 3));
}

// ---- cast X (4M el) and PE (1M el) to bf16, vectorized x4 ----
__global__ __launch_bounds__(256)
void cast_in(const float* __restrict__ X, const float* __restrict__ PE,
             ushortT* __restrict__ Xb, ushortT* __restrict__ PEb) {
  const size_t i4 = (size_t)blockIdx.x * 256 + threadIdx.x;
  const size_t NX = (size_t)4 * SEQ * DM / 4;
  const float4 v = (i4 < NX) ? *(const float4*)(X + i4 * 4)
                             : *(const float4*)(PE + (i4 - NX) * 4);
  ushortT o[4] = {f2bf(v.x), f2bf(v.y), f2bf(v.z), f2bf(v.w)};
  ushortT* dst = (i4 < NX) ? (Xb + i4 * 4) : (PEb + (i4 - NX) * 4);
  *(ulonglong1*)dst = *(ulonglong1*)o;
}

// ---- transpose 5 weights 512x512 fp32 -> bf16 [n][k], contiguous ----
__global__ __launch_bounds__(256)
void transpose_w(const float* __restrict__ w0, const float* __restrict__ w1,
                 const float* __restrict__ w2, const float* __restrict__ w3,
                 const float* __restrict__ w4, ushortT* __restrict__ out) {
  __shared__ float ts[32][33];
  const int z = blockIdx.z;
  const float* w = (z == 0) ? w0 : (z == 1) ? w1 : (z == 2) ? w2 : (z == 3) ? w3 : w4;
  ushortT* o = out + (size_t)z * DM * DM;
  const int k0 = blockIdx.x * 32, n0 = blockIdx.y * 32;
  const int tx = threadIdx.x, ty = threadIdx.y;
#pragma unroll
  for (int i = 0; i < 4; ++i)
    ts[ty + i * 8][tx] = w[(size_t)(k0 + ty + i * 8) * DM + n0 + tx];
  __syncthreads();
#pragma unroll
  for (int i = 0; i < 4; ++i)
    o[(size_t)(n0 + ty + i * 8) * DM + k0 + tx] = f2bf(ts[tx][ty + i * 8]);
}

// ---- LDS double-buffered bf16 MFMA GEMM, 128x128 tile, BK=32 ----
// ONE barrier per K-iteration (was two): store slab k+1 into buf[cur^1]
// while computing from buf[cur]. After iteration i's barrier every wave has
// drained its reads of buf[cur_i], so iteration i+1's write to it is safe.
__global__ __launch_bounds__(256)
void gemm_mfma(const ushortT* __restrict__ A, const ushortT* __restrict__ Bt,
               const float* __restrict__ ubv, const float* __restrict__ vbv,
               ushortT* __restrict__ qu, ushortT* __restrict__ qv,
               ushortT* __restrict__ kb, ushortT* __restrict__ vt,
               float* __restrict__ of, int mode) {
  __shared__ ushortT As[2][128][ASTR];
  __shared__ ushortT Bs[2][128][ASTR];
  const int tid = threadIdx.x;
  const int w = tid >> 6, lane = tid & 63;
  const int c = lane & 15, q = lane >> 4;
  const int wm = w >> 1, wn = w & 1;
  const int m0 = blockIdx.x * 128, n0 = blockIdx.y * 128;
  const int lr = tid >> 1, lh = (tid & 1) * 16;  // load row 0..127, k-half

  f32x4 acc[4][4];
#pragma unroll
  for (int mt = 0; mt < 4; ++mt)
#pragma unroll
    for (int nt = 0; nt < 4; ++nt) acc[mt][nt] = (f32x4){0.f, 0.f, 0.f, 0.f};

  const ushortT* Ar = A + (size_t)(m0 + lr) * DM + lh;
  const ushortT* Br = Bt + (size_t)(n0 + lr) * DM + lh;
  uint4 a0 = *(const uint4*)(Ar);
  uint4 a1 = *(const uint4*)(Ar + 8);
  uint4 b0 = *(const uint4*)(Br);
  uint4 b1 = *(const uint4*)(Br + 8);
  *(uint4*)&As[0][lr][lh] = a0; *(uint4*)&As[0][lr][lh + 8] = a1;
  *(uint4*)&Bs[0][lr][lh] = b0; *(uint4*)&Bs[0][lr][lh + 8] = b1;
  __syncthreads();

  int cur = 0;
  for (int k0 = 0; k0 < DM; k0 += 32) {
    const bool morek = (k0 + 32 < DM);
    if (morek) {                           // prefetch next slab (overlaps MFMA)
      a0 = *(const uint4*)(Ar + k0 + 32);
      a1 = *(const uint4*)(Ar + k0 + 40);
      b0 = *(const uint4*)(Br + k0 + 32);
      b1 = *(const uint4*)(Br + k0 + 40);
    }
    s16x8 af[4], bf[4];
#pragma unroll
    for (int mt = 0; mt < 4; ++mt)
      af[mt] = *(const s16x8*)&As[cur][wm * 64 + mt * 16 + c][q * 8];
#pragma unroll
    for (int nt = 0; nt < 4; ++nt)
      bf[nt] = *(const s16x8*)&Bs[cur][wn * 64 + nt * 16 + c][q * 8];
#pragma unroll
    for (int mt = 0; mt < 4; ++mt)
#pragma unroll
      for (int nt = 0; nt < 4; ++nt)
        acc[mt][nt] = MFMA16(af[mt], bf[nt], acc[mt][nt], 0, 0, 0);
    if (morek) {                           // stage into the idle buffer
      *(uint4*)&As[cur ^ 1][lr][lh] = a0; *(uint4*)&As[cur ^ 1][lr][lh + 8] = a1;
      *(uint4*)&Bs[cur ^ 1][lr][lh] = b0; *(uint4*)&Bs[cur ^ 1][lr][lh + 8] = b1;
      __syncthreads();                     // staging visible + reads drained
    }
    cur ^= 1;
  }

#pragma unroll
  for (int mt = 0; mt < 4; ++mt)
#pragma unroll
    for (int nt = 0; nt < 4; ++nt)
#pragma unroll
      for (int r = 0; r < 4; ++r) {
        const int gm = m0 + wm * 64 + mt * 16 + q * 4 + r;
        const int gn = n0 + wn * 64 + nt * 16 + c;
        const float v = acc[mt][nt][r];
        const int bb = gm >> 11, s = gm & (SEQ - 1);
        if (mode == 0) {
          const int z = gn >> 9, gn5 = gn & 511;
          const int h = gn5 >> 6, d = gn5 & 63;
          if (z == 0) {
            const size_t base = (((size_t)bb * NH + h) * SEQ + s) * DK + d;
            qu[base] = f2bf((v + ubv[gn5]) * QSCALE);
            qv[base] = f2bf((v + vbv[gn5]) * QSCALE);
          } else if (z == 1) {
            kb[(((size_t)bb * NH + h) * SEQ + s) * DK + d] = f2bf(v);
          } else {
            const int s_il = (s & ~31) | pinv(s & 31);
            vt[(((size_t)bb * NH + h) * DK + d) * SEQ + s_il] = f2bf(v);
          }
        } else if (mode == 3) {
          const int h = gn >> 6, d = gn & 63;
          qu[((size_t)h * PPAD + POFF + gm) * DK + d] = f2bf(v);
        } else {
          of[(size_t)gm * DM + gn] = v;
        }
      }
}

// ---- band GEMM helper: G = Qrow-block x P[tile*16 .. +15]  (P from L2) ----
static __device__ __forceinline__ f32x4 band_gemm(const ushortT* pb, int tile,
                                                  int c, int q, s16x8 a0, s16x8 a1) {
  const ushortT* pc = pb + (ptrdiff_t)(tile * 16 + c) * DK + q * 8;
  f32x4 G = {0.f, 0.f, 0.f, 0.f};
  G = MFMA16(a0, *(const s16x8*)pc, G, 0, 0, 0);
  G = MFMA16(a1, *(const s16x8*)(pc + 32), G, 0, 0, 0);
  return G;
}

// band GEMM from pre-loaded register fragments
static __device__ __forceinline__ f32x4 band_gemm_r(s16x8 a0, s16x8 a1,
                                                    s16x8 p0, s16x8 p1) {
  f32x4 G = {0.f, 0.f, 0.f, 0.f};
  G = MFMA16(a0, p0, G, 0, 0, 0);
  G = MFMA16(a1, p1, G, 0, 0, 0);
  return G;
}

// shear-transpose band triple -> per-Q-row slots (diagonal select via kcol)
static __device__ __forceinline__ void write_band(float (*E)[PSTR], int c, int m_w,
                                                  f32x4 b0, f32x4 b1, f32x4 b2) {
  const f32x4 bb[3] = {b0, b1, b2};
#pragma unroll
  for (int t = 0; t < 3; ++t)
#pragma unroll
    for (int r = 0; r < 4; ++r) {
      const int kcol = t * 16 + c + (m_w + r) - 15;
      if (kcol >= 0 && kcol < 32) E[m_w + r][pinv(kcol)] = bb[t][r];
    }
}

// ---- MFMA flash relative attention (ROUND-3 VERBATIM, best measured:
// 211-228 us attn / 358.8 total): LDS-staged K/V, TRANSPOSED scores, band
// software-pipelined one iteration ahead (double-buffered E1); iteration n
// combines with bands written during iteration n-1. Phase-B (diagonal,
// 2/64 iters) stays synchronous with separate E2.
__global__ __launch_bounds__(256, 3)
void attn_mfma(const ushortT* __restrict__ Qu, const ushortT* __restrict__ Qv,
               const ushortT* __restrict__ Kb, const ushortT* __restrict__ Vt,
               const ushortT* __restrict__ Pp, ushortT* __restrict__ ctxb) {
  const int n = blockIdx.x;
  const int xcd = n & 7, idx = n >> 3;      // XCD x serves h=x (L2 locality)
  const int b = idx >> 5, iblk = idx & 31;
  const int h = xcd, bh = b * 8 + h;
  const int tid = threadIdx.x;
  const int w = tid >> 6, lane = tid & 63;
  const int c = lane & 15, q = lane >> 4;
  const int i0 = iblk * 64;
  const int iw = i0 + w * 16;

  __shared__ ushortT Ks[64][KSTR];
  __shared__ ushortT Vs[64][KSTR];
  __shared__ float E1[4][2][16][PSTR];  // double-buffered pipelined band
  __shared__ float E2[4][16][PSTR];     // region-2 band (phase B only, sync)
  __shared__ float Lb[4][16];

  const ushortT* Qub = Qu + ((size_t)bh * SEQ + iw) * DK;
  const ushortT* Qvb = Qv + ((size_t)bh * SEQ + iw) * DK;
  const ushortT* Kbh = Kb + (size_t)bh * SEQ * DK;
  const ushortT* Vbh = Vt + (size_t)bh * DK * SEQ;
  const ushortT* Ph  = Pp + ((size_t)h * PPAD + POFF) * DK;

  const s16x8 qu0 = *(const s16x8*)(Qub + (size_t)c * DK + q * 8);
  const s16x8 qu1 = *(const s16x8*)(Qub + (size_t)c * DK + 32 + q * 8);
  const s16x8 qv0 = *(const s16x8*)(Qvb + (size_t)c * DK + q * 8);
  const s16x8 qv1 = *(const s16x8*)(Qvb + (size_t)c * DK + 32 + q * 8);
  const s16x8 qw0 = *(const s16x8*)(Qvb + (size_t)(c + 1) * DK + q * 8);
  const s16x8 qw1 = *(const s16x8*)(Qvb + (size_t)(c + 1) * DK + 32 + q * 8);

  // per-slot j-local offsets: pi(q*8+jj)
  int joff[8];
#pragma unroll
  for (int jj = 0; jj < 8; ++jj)
    joff[jj] = (jj < 4) ? (4 * q + jj) : (16 + 4 * q + (jj - 4));

  f32x4 O[4];
#pragma unroll
  for (int r = 0; r < 4; ++r) O[r] = (f32x4){0.f, 0.f, 0.f, 0.f};
  float lrow = 0.f;
  f32x4 e2c = (f32x4){0.f, 0.f, 0.f, 0.f};
  bool hv1 = false, hv2 = false;
  const int jt = iw & ~31;
  const int m_w = q * 4;

  // ---- prologue: stage chunk 0 ----
  {
    const ushortT* gk = Kbh;
    uint4 k0v = *(const uint4*)(gk + tid * 8);
    uint4 k1v = *(const uint4*)(gk + 2048 + tid * 8);
    const ushortT* gv = Vbh + (size_t)(tid >> 2) * SEQ + (tid & 3) * 16;
    uint4 v0v = *(const uint4*)gv;
    uint4 v1v = *(const uint4*)(gv + 8);
    *(uint4*)&Ks[tid >> 3][(tid & 7) * 8] = k0v;
    *(uint4*)&Ks[32 + (tid >> 3)][(tid & 7) * 8] = k1v;
    *(uint4*)&Vs[tid >> 2][(tid & 3) * 16] = v0v;
    *(uint4*)&Vs[tid >> 2][(tid & 3) * 16 + 8] = v1v;
  }
  __syncthreads();

  // ---- prologue: band(0) (phase A iff jt > 0; else iter 0 is phase B, sync)
  if (jt > 0) {
    const ushortT* pb1 = Ph + (ptrdiff_t)(0 - iw + SEQ - 16) * DK;
    f32x4 b0 = band_gemm(pb1, 0, c, q, qv0, qv1);
    f32x4 b1 = band_gemm(pb1, 1, c, q, qv0, qv1);
    e2c = band_gemm(pb1, 2, c, q, qv0, qv1);
    hv1 = true;
    write_band(E1[w][0], c, m_w, b0, b1, e2c);
  }

#define PV_FROM(pr, jl)                                                       \
  {                                                                           \
    lrow += pr[0] + pr[1] + pr[2] + pr[3] + pr[4] + pr[5] + pr[6] + pr[7];    \
    const s16x8 pa = pack8(pr);                                               \
    _Pragma("unroll")                                                         \
    for (int dt = 0; dt < 4; ++dt) {                                          \
      const s16x8 vb = *(const s16x8*)&Vs[dt * 16 + c][(jl) + q * 8];         \
      O[dt] = MFMA16(pa, vb, O[dt], 0, 0, 0);                                 \
    }                                                                         \
  }

  for (int ch = 0; ch < 32; ++ch) {
    const bool more = (ch + 1) < 32;
    uint4 k0v, k1v, v0v, v1v;
    if (more) {  // prefetch next chunk into registers (overlaps compute)
      const ushortT* gk = Kbh + (size_t)(ch + 1) * 64 * DK;
      k0v = *(const uint4*)(gk + tid * 8);
      k1v = *(const uint4*)(gk + 2048 + tid * 8);
      const ushortT* gv = Vbh + (size_t)(tid >> 2) * SEQ + (ch + 1) * 64 + (tid & 3) * 16;
      v0v = *(const uint4*)gv;
      v1v = *(const uint4*)(gv + 8);
    }
#pragma unroll
    for (int t = 0; t < 2; ++t) {
      const int nn = ch * 2 + t;
      const int j0 = nn * 32;
      const int jl = t * 32;
      const int drel = j0 - iw;
      const bool curB = (j0 >= jt) && (j0 < jt + 64);
      const int j0n = j0 + 32;
      const bool nxtB = (j0n >= jt) && (j0n < jt + 64);
      const bool haveNext = (nn + 1 < 64) && !nxtB;
      const bool nextA = (j0n < jt);

      // ---- prefetch next band's P tiles 1,2 into regs (used at iter end) --
      s16x8 p10, p11, p20, p21;
      const ushortT* pbn = nullptr;
      if (haveNext) {
        const int dreln = j0n - iw;
        pbn = nextA ? (Ph + (ptrdiff_t)(dreln + SEQ - 16) * DK)
                    : (Ph + (ptrdiff_t)(dreln - 17) * DK);
        const ushortT* pc1 = pbn + (ptrdiff_t)(16 + c) * DK + q * 8;
        const ushortT* pc2 = pbn + (ptrdiff_t)(32 + c) * DK + q * 8;
        p10 = *(const s16x8*)pc1;
        p11 = *(const s16x8*)(pc1 + 32);
        p20 = *(const s16x8*)pc2;
        p21 = *(const s16x8*)(pc2 + 32);
      }

      // ---- early E1 read (band written by this wave last iteration) ----
      float4 fA, fB;
      if (!curB) {
        const float* e1r = &E1[w][nn & 1][c][q * 8];
        fA = *(const float4*)e1r;
        fB = *(const float4*)(e1r + 4);
      }

      // transposed content scores: S^T[j=q*4+r (+16)][i=c], K from LDS
      f32x4 S0 = {0.f, 0.f, 0.f, 0.f}, S1 = {0.f, 0.f, 0.f, 0.f};
      {
        const ushortT* ka = &Ks[jl + c][q * 8];
        S0 = MFMA16(*(const s16x8*)ka, qu0, S0, 0, 0, 0);
        S0 = MFMA16(*(const s16x8*)(ka + 32), qu1, S0, 0, 0, 0);
        const ushortT* ka2 = &Ks[jl + 16 + c][q * 8];
        S1 = MFMA16(*(const s16x8*)ka2, qu0, S1, 0, 0, 0);
        S1 = MFMA16(*(const s16x8*)(ka2 + 32), qu1, S1, 0, 0, 0);
      }

      if (curB) {  // ---- synchronous two-region band at the diagonal ----
        {
          const ushortT* pb1 = Ph + (ptrdiff_t)(drel + SEQ - 16) * DK;
          f32x4 b0 = band_gemm(pb1, 0, c, q, qv0, qv1);
          f32x4 b1 = band_gemm(pb1, 1, c, q, qv0, qv1);
          f32x4 b2 = band_gemm(pb1, 2, c, q, qv0, qv1);
          write_band(E1[w][nn & 1], c, m_w, b0, b1, b2);
        }
        {
          const ushortT* pb2 = Ph + (ptrdiff_t)(drel - 17) * DK;
          f32x4 b0 = band_gemm(pb2, 0, c, q, qw0, qw1);
          f32x4 b1 = band_gemm(pb2, 1, c, q, qw0, qw1);
          f32x4 b2 = band_gemm(pb2, 2, c, q, qw0, qw1);
          write_band(E2[w], c, m_w, b0, b1, b2);
        }
        const float* e1r = &E1[w][nn & 1][c][q * 8];
        const float* e2r = &E2[w][c][q * 8];
        float4 aA = *(const float4*)e1r, aB = *(const float4*)(e1r + 4);
        float4 bA = *(const float4*)e2r, bB = *(const float4*)(e2r + 4);
        float f1[8] = {aA.x, aA.y, aA.z, aA.w, aB.x, aB.y, aB.z, aB.w};
        float f2[8] = {bA.x, bA.y, bA.z, bA.w, bB.x, bB.y, bB.z, bB.w};
        float sv[8] = {S0[0], S0[1], S0[2], S0[3], S1[0], S1[1], S1[2], S1[3]};
        float pr[8];
#pragma unroll
        for (int jj = 0; jj < 8; ++jj) {
          const int dlt = drel + joff[jj] - c;
          const float g = (dlt <= 0) ? f1[jj] : ((dlt == 1) ? 0.0f : f2[jj]);
          pr[jj] = fexp2(sv[jj] + g);
        }
        PV_FROM(pr, jl)
      } else {     // ---- common path: band was pipelined last iteration ----
        float pr[8] = {fexp2(S0[0] + fA.x), fexp2(S0[1] + fA.y),
                       fexp2(S0[2] + fA.z), fexp2(S0[3] + fA.w),
                       fexp2(S1[0] + fB.x), fexp2(S1[1] + fB.y),
                       fexp2(S1[2] + fB.z), fexp2(S1[3] + fB.w)};
        PV_FROM(pr, jl)
      }

      // ---- pipeline band(nn+1) into E1[(nn+1)&1] with prefetched P regs ---
      if (haveNext) {
        f32x4 b0, b1, b2;
        if (nextA) {
          if (hv1) b0 = e2c;
          else { b0 = band_gemm(pbn, 0, c, q, qv0, qv1); hv1 = true; }
          b1 = band_gemm_r(qv0, qv1, p10, p11);
          b2 = band_gemm_r(qv0, qv1, p20, p21);
        } else {
          if (hv2) b0 = e2c;
          else { b0 = band_gemm(pbn, 0, c, q, qw0, qw1); hv2 = true; }
          b1 = band_gemm_r(qw0, qw1, p10, p11);
          b2 = band_gemm_r(qw0, qw1, p20, p21);
        }
        e2c = b2;
        write_band(E1[w][(nn + 1) & 1], c, m_w, b0, b1, b2);
      }
    }
    __syncthreads();                     // all waves done reading Ks/Vs
    if (more) {
      *(uint4*)&Ks[tid >> 3][(tid & 7) * 8] = k0v;
      *(uint4*)&Ks[32 + (tid >> 3)][(tid & 7) * 8] = k1v;
      *(uint4*)&Vs[tid >> 2][(tid & 3) * 16] = v0v;
      *(uint4*)&Vs[tid >> 2][(tid & 3) * 16 + 8] = v1v;
    }
    __syncthreads();                     // staging visible
  }

  // ---- epilogue (rows exclusive to this wave) ----
  lrow += __shfl_xor(lrow, 16);
  lrow += __shfl_xor(lrow, 32);
  if (q == 0) Lb[w][c] = lrow;
  float inv[4];
#pragma unroll
  for (int r = 0; r < 4; ++r) inv[r] = 1.0f / Lb[w][q * 4 + r];
#pragma unroll
  for (int dt = 0; dt < 4; ++dt)
#pragma unroll
    for (int r = 0; r < 4; ++r) {
      const int i = iw + q * 4 + r;
      ctxb[((size_t)b * SEQ + i) * DM + h * DK + dt * 16 + c] = f2bf(O[dt][r] * inv[r]);
    }
}

extern "C" void kernel_launch(void* const* d_in, const int* in_sizes, int n_in,
                              void* d_out, int out_size, void* d_ws, size_t ws_size,
                              hipStream_t stream) {
  (void)in_sizes; (void)n_in; (void)out_size; (void)ws_size;
  const float* X   = (const float*)d_in[0];
  const float* PE  = (const float*)d_in[1];
  const float* Wq  = (const float*)d_in[2];
  const float* Wk  = (const float*)d_in[3];
  const float* Wv  = (const float*)d_in[4];
  const float* Wo  = (const float*)d_in[5];
  const float* Wp  = (const float*)d_in[6];
  const float* ubv = (const float*)d_in[7];
  const float* vbv = (const float*)d_in[8];

  const size_t NX = (size_t)4 * SEQ * DM;   // 4 Mi
  const size_t NP = (size_t)SEQ * DM;       // 1 Mi
  const size_t NW = (size_t)DM * DM;        // 256 Ki
  ushortT* Xb  = (ushortT*)d_ws;
  ushortT* PEb = Xb + NX;
  ushortT* Wt  = PEb + NP;                  // [Wq^T;Wk^T;Wv^T;Wp^T;Wo^T] bf16
  ushortT* qu  = Wt + 5 * NW;
  ushortT* qv  = qu + NX;
  ushortT* kb  = qv + NX;                   // qw overread from qv lands here: safe
  ushortT* vt  = kb + NX;
  ushortT* pp  = vt + NX;                   // NH*PPAD*DK
  ushortT* ctx = pp + (size_t)NH * PPAD * DK;
  float* outp = (float*)d_out;

  hipLaunchKernelGGL(cast_in, dim3((NX + NP) / 4 / 256), dim3(256), 0, stream, X, PE, Xb, PEb);
  hipLaunchKernelGGL(transpose_w, dim3(16, 16, 5), dim3(32, 8), 0, stream, Wq, Wk, Wv, Wp, Wo, Wt);
  dim3 blk(256);
  hipLaunchKernelGGL(gemm_mfma, dim3(64, 12), blk, 0, stream, Xb, Wt, ubv, vbv,
                     qu, qv, kb, vt, (float*)nullptr, 0);
  hipLaunchKernelGGL(gemm_mfma, dim3(16, 4), blk, 0, stream, PEb, Wt + 3 * NW, ubv, vbv,
                     pp, (ushortT*)nullptr, (ushortT*)nullptr, (ushortT*)nullptr, (float*)nullptr, 3);
  hipLaunchKernelGGL(attn_mfma, dim3(1024), blk, 0, stream, qu, qv, kb, vt, pp, ctx);
  hipLaunchKernelGGL(gemm_mfma, dim3(64, 4), blk, 0, stream, ctx, Wt + 4 * NW, ubv, vbv,
                     (ushortT*)nullptr, (ushortT*)nullptr, (ushortT*)nullptr, (ushortT*)nullptr, outp, 4);
}

// Round 9
// 464.882 us; speedup vs baseline: 1.1354x; 1.0145x over previous
//
#include <hip/hip_runtime.h>
#include <hip/hip_bf16.h>
#include <math.h>

#define SEQ 2048
#define NH 8
#define DK 64
#define DM 512
#define QSCALE 0.18033688011112042f  // 0.125 * log2(e): exp(x*0.125) == exp2(x*QSCALE)
#define PPAD (SEQ + 128)
#define POFF 64
#define KSTR 72   // K/V LDS row stride (bf16 el): 144B = 16B-aligned
#define PSTR 36   // E1/E2 LDS row stride (f32)
#define ASTR 34   // GEMM LDS row stride (bf16 el): 68B -> 17-bank row offset

typedef unsigned short ushortT;
typedef short s16x8 __attribute__((ext_vector_type(8)));
typedef float f32x4 __attribute__((ext_vector_type(4)));

#define MFMA16 __builtin_amdgcn_mfma_f32_16x16x32_bf16

static __device__ __forceinline__ ushortT f2bf(float x) {
  __hip_bfloat16 h = __float2bfloat16(x);
  ushortT u;
  __builtin_memcpy(&u, &h, 2);
  return u;
}

static __device__ __forceinline__ float fexp2(float x) {
  return __builtin_amdgcn_exp2f(x);
}

static __device__ __forceinline__ s16x8 pack8(const float* p) {
  ushortT u[8];
#pragma unroll
  for (int i = 0; i < 8; ++i) u[i] = f2bf(p[i]);
  s16x8 out;
  __builtin_memcpy(&out, u, 16);
  return out;
}

// pi^-1: j-local column -> A-frag k-slot  (pi(q*8+jj) = jj<4 ? 4q+jj : 16+4q+jj-4)
static __device__ __forceinline__ int pinv(int j) {
  return (j < 16) ? ((j >> 2) * 8 + (j & 3)) : (((j >> 2) - 4) * 8 + 4 + (j & 3));
}

// ---- cast X (4M el) and PE (1M el) to bf16, vectorized x4 ----
__global__ __launch_bounds__(256)
void cast_in(const float* __restrict__ X, const float* __restrict__ PE,
             ushortT* __restrict__ Xb, ushortT* __restrict__ PEb) {
  const size_t i4 = (size_t)blockIdx.x * 256 + threadIdx.x;
  const size_t NX = (size_t)4 * SEQ * DM / 4;
  const float4 v = (i4 < NX) ? *(const float4*)(X + i4 * 4)
                             : *(const float4*)(PE + (i4 - NX) * 4);
  ushortT o[4] = {f2bf(v.x), f2bf(v.y), f2bf(v.z), f2bf(v.w)};
  ushortT* dst = (i4 < NX) ? (Xb + i4 * 4) : (PEb + (i4 - NX) * 4);
  *(ulonglong1*)dst = *(ulonglong1*)o;
}

// ---- transpose 5 weights 512x512 fp32 -> bf16 [n][k], contiguous ----
__global__ __launch_bounds__(256)
void transpose_w(const float* __restrict__ w0, const float* __restrict__ w1,
                 const float* __restrict__ w2, const float* __restrict__ w3,
                 const float* __restrict__ w4, ushortT* __restrict__ out) {
  __shared__ float ts[32][33];
  const int z = blockIdx.z;
  const float* w = (z == 0) ? w0 : (z == 1) ? w1 : (z == 2) ? w2 : (z == 3) ? w3 : w4;
  ushortT* o = out + (size_t)z * DM * DM;
  const int k0 = blockIdx.x * 32, n0 = blockIdx.y * 32;
  const int tx = threadIdx.x, ty = threadIdx.y;
#pragma unroll
  for (int i = 0; i < 4; ++i)
    ts[ty + i * 8][tx] = w[(size_t)(k0 + ty + i * 8) * DM + n0 + tx];
  __syncthreads();
#pragma unroll
  for (int i = 0; i < 4; ++i)
    o[(size_t)(n0 + ty + i * 8) * DM + k0 + tx] = f2bf(ts[tx][ty + i * 8]);
}

// ---- LDS-staged bf16 MFMA GEMM, 128x128 tile, BK=32 (m93 pattern) ----
__global__ __launch_bounds__(256)
void gemm_mfma(const ushortT* __restrict__ A, const ushortT* __restrict__ Bt,
               const float* __restrict__ ubv, const float* __restrict__ vbv,
               ushortT* __restrict__ qu, ushortT* __restrict__ qv,
               ushortT* __restrict__ kb, ushortT* __restrict__ vt,
               float* __restrict__ of, int mode) {
  __shared__ ushortT As[128][ASTR];
  __shared__ ushortT Bs[128][ASTR];
  const int tid = threadIdx.x;
  const int w = tid >> 6, lane = tid & 63;
  const int c = lane & 15, q = lane >> 4;
  const int wm = w >> 1, wn = w & 1;
  const int m0 = blockIdx.x * 128, n0 = blockIdx.y * 128;
  const int lr = tid >> 1, lh = (tid & 1) * 16;  // load row 0..127, k-half

  f32x4 acc[4][4];
#pragma unroll
  for (int mt = 0; mt < 4; ++mt)
#pragma unroll
    for (int nt = 0; nt < 4; ++nt) acc[mt][nt] = (f32x4){0.f, 0.f, 0.f, 0.f};

  const ushortT* Ar = A + (size_t)(m0 + lr) * DM + lh;
  const ushortT* Br = Bt + (size_t)(n0 + lr) * DM + lh;
  uint4 a0 = *(const uint4*)(Ar);
  uint4 a1 = *(const uint4*)(Ar + 8);
  uint4 b0 = *(const uint4*)(Br);
  uint4 b1 = *(const uint4*)(Br + 8);

  for (int k0 = 0; k0 < DM; k0 += 32) {
    __syncthreads();                       // prior compute done reading LDS
    *(uint4*)&As[lr][lh] = a0; *(uint4*)&As[lr][lh + 8] = a1;
    *(uint4*)&Bs[lr][lh] = b0; *(uint4*)&Bs[lr][lh + 8] = b1;
    __syncthreads();                       // staging visible
    if (k0 + 32 < DM) {                    // prefetch next slab (overlaps MFMA)
      a0 = *(const uint4*)(Ar + k0 + 32);
      a1 = *(const uint4*)(Ar + k0 + 40);
      b0 = *(const uint4*)(Br + k0 + 32);
      b1 = *(const uint4*)(Br + k0 + 40);
    }
    s16x8 af[4], bf[4];
#pragma unroll
    for (int mt = 0; mt < 4; ++mt)
      af[mt] = *(const s16x8*)&As[wm * 64 + mt * 16 + c][q * 8];
#pragma unroll
    for (int nt = 0; nt < 4; ++nt)
      bf[nt] = *(const s16x8*)&Bs[wn * 64 + nt * 16 + c][q * 8];
#pragma unroll
    for (int mt = 0; mt < 4; ++mt)
#pragma unroll
      for (int nt = 0; nt < 4; ++nt)
        acc[mt][nt] = MFMA16(af[mt], bf[nt], acc[mt][nt], 0, 0, 0);
  }

#pragma unroll
  for (int mt = 0; mt < 4; ++mt)
#pragma unroll
    for (int nt = 0; nt < 4; ++nt)
#pragma unroll
      for (int r = 0; r < 4; ++r) {
        const int gm = m0 + wm * 64 + mt * 16 + q * 4 + r;
        const int gn = n0 + wn * 64 + nt * 16 + c;
        const float v = acc[mt][nt][r];
        const int bb = gm >> 11, s = gm & (SEQ - 1);
        if (mode == 0) {
          const int z = gn >> 9, gn5 = gn & 511;
          const int h = gn5 >> 6, d = gn5 & 63;
          if (z == 0) {
            const size_t base = (((size_t)bb * NH + h) * SEQ + s) * DK + d;
            qu[base] = f2bf((v + ubv[gn5]) * QSCALE);
            qv[base] = f2bf((v + vbv[gn5]) * QSCALE);
          } else if (z == 1) {
            kb[(((size_t)bb * NH + h) * SEQ + s) * DK + d] = f2bf(v);
          } else {
            const int s_il = (s & ~31) | pinv(s & 31);
            vt[(((size_t)bb * NH + h) * DK + d) * SEQ + s_il] = f2bf(v);
          }
        } else if (mode == 3) {
          const int h = gn >> 6, d = gn & 63;
          qu[((size_t)h * PPAD + POFF + gm) * DK + d] = f2bf(v);
        } else {
          of[(size_t)gm * DM + gn] = v;
        }
      }
}

// ---- band GEMM helper: G = Qrow-block x P[tile*16 .. +15]  (P from L2) ----
static __device__ __forceinline__ f32x4 band_gemm(const ushortT* pb, int tile,
                                                  int c, int q, s16x8 a0, s16x8 a1) {
  const ushortT* pc = pb + (ptrdiff_t)(tile * 16 + c) * DK + q * 8;
  f32x4 G = {0.f, 0.f, 0.f, 0.f};
  G = MFMA16(a0, *(const s16x8*)pc, G, 0, 0, 0);
  G = MFMA16(a1, *(const s16x8*)(pc + 32), G, 0, 0, 0);
  return G;
}

// band GEMM from pre-loaded register fragments
static __device__ __forceinline__ f32x4 band_gemm_r(s16x8 a0, s16x8 a1,
                                                    s16x8 p0, s16x8 p1) {
  f32x4 G = {0.f, 0.f, 0.f, 0.f};
  G = MFMA16(a0, p0, G, 0, 0, 0);
  G = MFMA16(a1, p1, G, 0, 0, 0);
  return G;
}

// shear-transpose band triple -> per-Q-row slots (diagonal select via kcol)
static __device__ __forceinline__ void write_band(float (*E)[PSTR], int c, int m_w,
                                                  f32x4 b0, f32x4 b1, f32x4 b2) {
  const f32x4 bb[3] = {b0, b1, b2};
#pragma unroll
  for (int t = 0; t < 3; ++t)
#pragma unroll
    for (int r = 0; r < 4; ++r) {
      const int kcol = t * 16 + c + (m_w + r) - 15;
      if (kcol >= 0 && kcol < 32) E[m_w + r][pinv(kcol)] = bb[t][r];
    }
}

// ---- MFMA flash relative attention: LDS-staged K/V, TRANSPOSED scores,
// band SOFTWARE-PIPELINED one iteration ahead (double-buffered E1):
// iteration n combines with bands written during iteration n-1, so neither
// the P global-load latency nor the E-band LDS shear round trip sits on the
// exp/PV critical chain. Phase-B (diagonal, 2/64 iters) stays synchronous.
__global__ __launch_bounds__(256, 3)
void attn_mfma(const ushortT* __restrict__ Qu, const ushortT* __restrict__ Qv,
               const ushortT* __restrict__ Kb, const ushortT* __restrict__ Vt,
               const ushortT* __restrict__ Pp, ushortT* __restrict__ ctxb) {
  const int n = blockIdx.x;
  const int xcd = n & 7, idx = n >> 3;      // XCD x serves h=x (L2 locality)
  const int b = idx >> 5, iblk = idx & 31;
  const int h = xcd, bh = b * 8 + h;
  const int tid = threadIdx.x;
  const int w = tid >> 6, lane = tid & 63;
  const int c = lane & 15, q = lane >> 4;
  const int i0 = iblk * 64;
  const int iw = i0 + w * 16;

  __shared__ ushortT Ks[64][KSTR];
  __shared__ ushortT Vs[64][KSTR];
  __shared__ float E1[4][2][16][PSTR];  // double-buffered pipelined band
  __shared__ float E2[4][16][PSTR];     // region-2 band (phase B only, sync)
  __shared__ float Lb[4][16];

  const ushortT* Qub = Qu + ((size_t)bh * SEQ + iw) * DK;
  const ushortT* Qvb = Qv + ((size_t)bh * SEQ + iw) * DK;
  const ushortT* Kbh = Kb + (size_t)bh * SEQ * DK;
  const ushortT* Vbh = Vt + (size_t)bh * DK * SEQ;
  const ushortT* Ph  = Pp + ((size_t)h * PPAD + POFF) * DK;

  const s16x8 qu0 = *(const s16x8*)(Qub + (size_t)c * DK + q * 8);
  const s16x8 qu1 = *(const s16x8*)(Qub + (size_t)c * DK + 32 + q * 8);
  const s16x8 qv0 = *(const s16x8*)(Qvb + (size_t)c * DK + q * 8);
  const s16x8 qv1 = *(const s16x8*)(Qvb + (size_t)c * DK + 32 + q * 8);
  const s16x8 qw0 = *(const s16x8*)(Qvb + (size_t)(c + 1) * DK + q * 8);
  const s16x8 qw1 = *(const s16x8*)(Qvb + (size_t)(c + 1) * DK + 32 + q * 8);

  // per-slot j-local offsets: pi(q*8+jj)
  int joff[8];
#pragma unroll
  for (int jj = 0; jj < 8; ++jj)
    joff[jj] = (jj < 4) ? (4 * q + jj) : (16 + 4 * q + (jj - 4));

  f32x4 O[4];
#pragma unroll
  for (int r = 0; r < 4; ++r) O[r] = (f32x4){0.f, 0.f, 0.f, 0.f};
  float lrow = 0.f;
  f32x4 e2c = (f32x4){0.f, 0.f, 0.f, 0.f};
  bool hv1 = false, hv2 = false;
  const int jt = iw & ~31;
  const int m_w = q * 4;

  // ---- prologue: stage chunk 0 ----
  {
    const ushortT* gk = Kbh;
    uint4 k0v = *(const uint4*)(gk + tid * 8);
    uint4 k1v = *(const uint4*)(gk + 2048 + tid * 8);
    const ushortT* gv = Vbh + (size_t)(tid >> 2) * SEQ + (tid & 3) * 16;
    uint4 v0v = *(const uint4*)gv;
    uint4 v1v = *(const uint4*)(gv + 8);
    *(uint4*)&Ks[tid >> 3][(tid & 7) * 8] = k0v;
    *(uint4*)&Ks[32 + (tid >> 3)][(tid & 7) * 8] = k1v;
    *(uint4*)&Vs[tid >> 2][(tid & 3) * 16] = v0v;
    *(uint4*)&Vs[tid >> 2][(tid & 3) * 16 + 8] = v1v;
  }
  __syncthreads();

  // ---- prologue: band(0) (phase A iff jt > 0; else n=0 is phase B, sync)
  if (jt > 0) {
    const ushortT* pb1 = Ph + (ptrdiff_t)(0 - iw + SEQ - 16) * DK;
    f32x4 b0 = band_gemm(pb1, 0, c, q, qv0, qv1);
    f32x4 b1 = band_gemm(pb1, 1, c, q, qv0, qv1);
    e2c = band_gemm(pb1, 2, c, q, qv0, qv1);
    hv1 = true;
    write_band(E1[w][0], c, m_w, b0, b1, e2c);
  }

#define PV_FROM(pr, jl)                                                       \
  {                                                                           \
    lrow += pr[0] + pr[1] + pr[2] + pr[3] + pr[4] + pr[5] + pr[6] + pr[7];    \
    const s16x8 pa = pack8(pr);                                               \
    _Pragma("unroll")                                                         \
    for (int dt = 0; dt < 4; ++dt) {                                          \
      const s16x8 vb = *(const s16x8*)&Vs[dt * 16 + c][(jl) + q * 8];         \
      O[dt] = MFMA16(pa, vb, O[dt], 0, 0, 0);                                 \
    }                                                                         \
  }

  for (int ch = 0; ch < 32; ++ch) {
    const bool more = (ch + 1) < 32;
    uint4 k0v, k1v, v0v, v1v;
    if (more) {  // prefetch next chunk into registers (overlaps compute)
      const ushortT* gk = Kbh + (size_t)(ch + 1) * 64 * DK;
      k0v = *(const uint4*)(gk + tid * 8);
      k1v = *(const uint4*)(gk + 2048 + tid * 8);
      const ushortT* gv = Vbh + (size_t)(tid >> 2) * SEQ + (ch + 1) * 64 + (tid & 3) * 16;
      v0v = *(const uint4*)gv;
      v1v = *(const uint4*)(gv + 8);
    }
#pragma unroll
    for (int t = 0; t < 2; ++t) {
      const int nn = ch * 2 + t;
      const int j0 = nn * 32;
      const int jl = t * 32;
      const int drel = j0 - iw;
      const bool curB = (j0 >= jt) && (j0 < jt + 64);
      const int j0n = j0 + 32;
      const bool nxtB = (j0n >= jt) && (j0n < jt + 64);
      const bool haveNext = (nn + 1 < 64) && !nxtB;
      const bool nextA = (j0n < jt);

      // ---- prefetch next band's P tiles 1,2 into regs (used at iter end) --
      s16x8 p10, p11, p20, p21;
      const ushortT* pbn = nullptr;
      if (haveNext) {
        const int dreln = j0n - iw;
        pbn = nextA ? (Ph + (ptrdiff_t)(dreln + SEQ - 16) * DK)
                    : (Ph + (ptrdiff_t)(dreln - 17) * DK);
        const ushortT* pc1 = pbn + (ptrdiff_t)(16 + c) * DK + q * 8;
        const ushortT* pc2 = pbn + (ptrdiff_t)(32 + c) * DK + q * 8;
        p10 = *(const s16x8*)pc1;
        p11 = *(const s16x8*)(pc1 + 32);
        p20 = *(const s16x8*)pc2;
        p21 = *(const s16x8*)(pc2 + 32);
      }

      // ---- early E1 read (band written by this wave last iteration) ----
      float4 fA, fB;
      if (!curB) {
        const float* e1r = &E1[w][nn & 1][c][q * 8];
        fA = *(const float4*)e1r;
        fB = *(const float4*)(e1r + 4);
      }

      // transposed content scores: S^T[j=q*4+r (+16)][i=c], K from LDS
      f32x4 S0 = {0.f, 0.f, 0.f, 0.f}, S1 = {0.f, 0.f, 0.f, 0.f};
      {
        const ushortT* ka = &Ks[jl + c][q * 8];
        S0 = MFMA16(*(const s16x8*)ka, qu0, S0, 0, 0, 0);
        S0 = MFMA16(*(const s16x8*)(ka + 32), qu1, S0, 0, 0, 0);
        const ushortT* ka2 = &Ks[jl + 16 + c][q * 8];
        S1 = MFMA16(*(const s16x8*)ka2, qu0, S1, 0, 0, 0);
        S1 = MFMA16(*(const s16x8*)(ka2 + 32), qu1, S1, 0, 0, 0);
      }

      if (curB) {  // ---- synchronous two-region band at the diagonal ----
        {
          const ushortT* pb1 = Ph + (ptrdiff_t)(drel + SEQ - 16) * DK;
          f32x4 b0 = band_gemm(pb1, 0, c, q, qv0, qv1);
          f32x4 b1 = band_gemm(pb1, 1, c, q, qv0, qv1);
          f32x4 b2 = band_gemm(pb1, 2, c, q, qv0, qv1);
          write_band(E1[w][nn & 1], c, m_w, b0, b1, b2);
        }
        {
          const ushortT* pb2 = Ph + (ptrdiff_t)(drel - 17) * DK;
          f32x4 b0 = band_gemm(pb2, 0, c, q, qw0, qw1);
          f32x4 b1 = band_gemm(pb2, 1, c, q, qw0, qw1);
          f32x4 b2 = band_gemm(pb2, 2, c, q, qw0, qw1);
          write_band(E2[w], c, m_w, b0, b1, b2);
        }
        const float* e1r = &E1[w][nn & 1][c][q * 8];
        const float* e2r = &E2[w][c][q * 8];
        float4 aA = *(const float4*)e1r, aB = *(const float4*)(e1r + 4);
        float4 bA = *(const float4*)e2r, bB = *(const float4*)(e2r + 4);
        float f1[8] = {aA.x, aA.y, aA.z, aA.w, aB.x, aB.y, aB.z, aB.w};
        float f2[8] = {bA.x, bA.y, bA.z, bA.w, bB.x, bB.y, bB.z, bB.w};
        float sv[8] = {S0[0], S0[1], S0[2], S0[3], S1[0], S1[1], S1[2], S1[3]};
        float pr[8];
#pragma unroll
        for (int jj = 0; jj < 8; ++jj) {
          const int dlt = drel + joff[jj] - c;
          const float g = (dlt <= 0) ? f1[jj] : ((dlt == 1) ? 0.0f : f2[jj]);
          pr[jj] = fexp2(sv[jj] + g);
        }
        PV_FROM(pr, jl)
      } else {     // ---- common path: band was pipelined last iteration ----
        float pr[8] = {fexp2(S0[0] + fA.x), fexp2(S0[1] + fA.y),
                       fexp2(S0[2] + fA.z), fexp2(S0[3] + fA.w),
                       fexp2(S1[0] + fB.x), fexp2(S1[1] + fB.y),
                       fexp2(S1[2] + fB.z), fexp2(S1[3] + fB.w)};
        PV_FROM(pr, jl)
      }

      // ---- pipeline band(nn+1) into E1[(nn+1)&1] with prefetched P regs ---
      if (haveNext) {
        f32x4 b0, b1, b2;
        if (nextA) {
          if (hv1) b0 = e2c;
          else { b0 = band_gemm(pbn, 0, c, q, qv0, qv1); hv1 = true; }
          b1 = band_gemm_r(qv0, qv1, p10, p11);
          b2 = band_gemm_r(qv0, qv1, p20, p21);
        } else {
          if (hv2) b0 = e2c;
          else { b0 = band_gemm(pbn, 0, c, q, qw0, qw1); hv2 = true; }
          b1 = band_gemm_r(qw0, qw1, p10, p11);
          b2 = band_gemm_r(qw0, qw1, p20, p21);
        }
        e2c = b2;
        write_band(E1[w][(nn + 1) & 1], c, m_w, b0, b1, b2);
      }
    }
    __syncthreads();                     // all waves done reading Ks/Vs
    if (more) {
      *(uint4*)&Ks[tid >> 3][(tid & 7) * 8] = k0v;
      *(uint4*)&Ks[32 + (tid >> 3)][(tid & 7) * 8] = k1v;
      *(uint4*)&Vs[tid >> 2][(tid & 3) * 16] = v0v;
      *(uint4*)&Vs[tid >> 2][(tid & 3) * 16 + 8] = v1v;
    }
    __syncthreads();                     // staging visible
  }

  // ---- epilogue (rows exclusive to this wave) ----
  lrow += __shfl_xor(lrow, 16);
  lrow += __shfl_xor(lrow, 32);
  if (q == 0) Lb[w][c] = lrow;
  float inv[4];
#pragma unroll
  for (int r = 0; r < 4; ++r) inv[r] = 1.0f / Lb[w][q * 4 + r];
#pragma unroll
  for (int dt = 0; dt < 4; ++dt)
#pragma unroll
    for (int r = 0; r < 4; ++r) {
      const int i = iw + q * 4 + r;
      ctxb[((size_t)b * SEQ + i) * DM + h * DK + dt * 16 + c] = f2bf(O[dt][r] * inv[r]);
    }
}

extern "C" void kernel_launch(void* const* d_in, const int* in_sizes, int n_in,
                              void* d_out, int out_size, void* d_ws, size_t ws_size,
                              hipStream_t stream) {
  (void)in_sizes; (void)n_in; (void)out_size; (void)ws_size;
  const float* X   = (const float*)d_in[0];
  const float* PE  = (const float*)d_in[1];
  const float* Wq  = (const float*)d_in[2];
  const float* Wk  = (const float*)d_in[3];
  const float* Wv  = (const float*)d_in[4];
  const float* Wo  = (const float*)d_in[5];
  const float* Wp  = (const float*)d_in[6];
  const float* ubv = (const float*)d_in[7];
  const float* vbv = (const float*)d_in[8];

  const size_t NX = (size_t)4 * SEQ * DM;   // 4 Mi
  const size_t NP = (size_t)SEQ * DM;       // 1 Mi
  const size_t NW = (size_t)DM * DM;        // 256 Ki
  ushortT* Xb  = (ushortT*)d_ws;
  ushortT* PEb = Xb + NX;
  ushortT* Wt  = PEb + NP;                  // [Wq^T;Wk^T;Wv^T;Wp^T;Wo^T] bf16
  ushortT* qu  = Wt + 5 * NW;
  ushortT* qv  = qu + NX;
  ushortT* kb  = qv + NX;                   // qw overread from qv lands here: safe
  ushortT* vt  = kb + NX;
  ushortT* pp  = vt + NX;                   // NH*PPAD*DK
  ushortT* ctx = pp + (size_t)NH * PPAD * DK;
  float* outp = (float*)d_out;

  hipLaunchKernelGGL(cast_in, dim3((NX + NP) / 4 / 256), dim3(256), 0, stream, X, PE, Xb, PEb);
  hipLaunchKernelGGL(transpose_w, dim3(16, 16, 5), dim3(32, 8), 0, stream, Wq, Wk, Wv, Wp, Wo, Wt);
  dim3 blk(256);
  hipLaunchKernelGGL(gemm_mfma, dim3(64, 12), blk, 0, stream, Xb, Wt, ubv, vbv,
                     qu, qv, kb, vt, (float*)nullptr, 0);
  hipLaunchKernelGGL(gemm_mfma, dim3(16, 4), blk, 0, stream, PEb, Wt + 3 * NW, ubv, vbv,
                     pp, (ushortT*)nullptr, (ushortT*)nullptr, (ushortT*)nullptr, (float*)nullptr, 3);
  hipLaunchKernelGGL(attn_mfma, dim3(1024), blk, 0, stream, qu, qv, kb, vt, pp, ctx);
  hipLaunchKernelGGL(gemm_mfma, dim3(64, 4), blk, 0, stream, ctx, Wt + 4 * NW, ubv, vbv,
                     (ushortT*)nullptr, (ushortT*)nullptr, (ushortT*)nullptr, (ushortT*)nullptr, outp, 4);
}

// Round 10
// 357.223 us; speedup vs baseline: 1.4776x; 1.3014x over previous
//
#include <hip/hip_runtime.h>
#include <hip/hip_bf16.h>
#include <math.h>

#define SEQ 2048
#define NH 8
#define DK 64
#define DM 512
#define QSCALE 0.18033688011112042f  // 0.125 * log2(e): exp(x*0.125) == exp2(x*QSCALE)
#define PPAD (SEQ + 128)
#define POFF 64
#define KSTR 72   // K/V LDS row stride (bf16 el): 144B = 16B-aligned, 2-way banks
#define PSTR 36   // E1/E2 LDS row stride (f32)
#define ASTR 34   // GEMM LDS row stride (bf16 el): 68B -> 17-bank row offset

typedef unsigned short ushortT;
typedef short s16x8 __attribute__((ext_vector_type(8)));
typedef float f32x4 __attribute__((ext_vector_type(4)));

#define MFMA16 __builtin_amdgcn_mfma_f32_16x16x32_bf16

static __device__ __forceinline__ ushortT f2bf(float x) {
  __hip_bfloat16 h = __float2bfloat16(x);
  ushortT u;
  __builtin_memcpy(&u, &h, 2);
  return u;
}

static __device__ __forceinline__ float fexp2(float x) {
  return __builtin_amdgcn_exp2f(x);
}

static __device__ __forceinline__ s16x8 pack8(const float* p) {
  ushortT u[8];
#pragma unroll
  for (int i = 0; i < 8; ++i) u[i] = f2bf(p[i]);
  s16x8 out;
  __builtin_memcpy(&out, u, 16);
  return out;
}

// pi^-1: j-local column -> A-frag k-slot  (pi(q*8+jj) = jj<4 ? 4q+jj : 16+4q+jj-4)
static __device__ __forceinline__ int pinv(int j) {
  return (j < 16) ? ((j >> 2) * 8 + (j & 3)) : (((j >> 2) - 4) * 8 + 4 + (j & 3));
}

// ---- cast X (4M el) and PE (1M el) to bf16, vectorized x4 ----
__global__ __launch_bounds__(256)
void cast_in(const float* __restrict__ X, const float* __restrict__ PE,
             ushortT* __restrict__ Xb, ushortT* __restrict__ PEb) {
  const size_t i4 = (size_t)blockIdx.x * 256 + threadIdx.x;
  const size_t NX = (size_t)4 * SEQ * DM / 4;
  const float4 v = (i4 < NX) ? *(const float4*)(X + i4 * 4)
                             : *(const float4*)(PE + (i4 - NX) * 4);
  ushortT o[4] = {f2bf(v.x), f2bf(v.y), f2bf(v.z), f2bf(v.w)};
  ushortT* dst = (i4 < NX) ? (Xb + i4 * 4) : (PEb + (i4 - NX) * 4);
  *(ulonglong1*)dst = *(ulonglong1*)o;
}

// ---- transpose 5 weights 512x512 fp32 -> bf16 [n][k], contiguous ----
__global__ __launch_bounds__(256)
void transpose_w(const float* __restrict__ w0, const float* __restrict__ w1,
                 const float* __restrict__ w2, const float* __restrict__ w3,
                 const float* __restrict__ w4, ushortT* __restrict__ out) {
  __shared__ float ts[32][33];
  const int z = blockIdx.z;
  const float* w = (z == 0) ? w0 : (z == 1) ? w1 : (z == 2) ? w2 : (z == 3) ? w3 : w4;
  ushortT* o = out + (size_t)z * DM * DM;
  const int k0 = blockIdx.x * 32, n0 = blockIdx.y * 32;
  const int tx = threadIdx.x, ty = threadIdx.y;
#pragma unroll
  for (int i = 0; i < 4; ++i)
    ts[ty + i * 8][tx] = w[(size_t)(k0 + ty + i * 8) * DM + n0 + tx];
  __syncthreads();
#pragma unroll
  for (int i = 0; i < 4; ++i)
    o[(size_t)(n0 + ty + i * 8) * DM + k0 + tx] = f2bf(ts[tx][ty + i * 8]);
}

// ---- LDS-staged bf16 MFMA GEMM, 128x128 tile, BK=32 (m93 pattern) ----
__global__ __launch_bounds__(256)
void gemm_mfma(const ushortT* __restrict__ A, const ushortT* __restrict__ Bt,
               const float* __restrict__ ubv, const float* __restrict__ vbv,
               ushortT* __restrict__ qu, ushortT* __restrict__ qv,
               ushortT* __restrict__ kb, ushortT* __restrict__ vt,
               float* __restrict__ of, int mode) {
  __shared__ ushortT As[128][ASTR];
  __shared__ ushortT Bs[128][ASTR];
  const int tid = threadIdx.x;
  const int w = tid >> 6, lane = tid & 63;
  const int c = lane & 15, q = lane >> 4;
  const int wm = w >> 1, wn = w & 1;
  const int m0 = blockIdx.x * 128, n0 = blockIdx.y * 128;
  const int lr = tid >> 1, lh = (tid & 1) * 16;  // load row 0..127, k-half

  f32x4 acc[4][4];
#pragma unroll
  for (int mt = 0; mt < 4; ++mt)
#pragma unroll
    for (int nt = 0; nt < 4; ++nt) acc[mt][nt] = (f32x4){0.f, 0.f, 0.f, 0.f};

  const ushortT* Ar = A + (size_t)(m0 + lr) * DM + lh;
  const ushortT* Br = Bt + (size_t)(n0 + lr) * DM + lh;
  uint4 a0 = *(const uint4*)(Ar);
  uint4 a1 = *(const uint4*)(Ar + 8);
  uint4 b0 = *(const uint4*)(Br);
  uint4 b1 = *(const uint4*)(Br + 8);

  for (int k0 = 0; k0 < DM; k0 += 32) {
    __syncthreads();                       // prior compute done reading LDS
    *(uint4*)&As[lr][lh] = a0; *(uint4*)&As[lr][lh + 8] = a1;
    *(uint4*)&Bs[lr][lh] = b0; *(uint4*)&Bs[lr][lh + 8] = b1;
    __syncthreads();                       // staging visible
    if (k0 + 32 < DM) {                    // prefetch next slab (overlaps MFMA)
      a0 = *(const uint4*)(Ar + k0 + 32);
      a1 = *(const uint4*)(Ar + k0 + 40);
      b0 = *(const uint4*)(Br + k0 + 32);
      b1 = *(const uint4*)(Br + k0 + 40);
    }
    s16x8 af[4], bf[4];
#pragma unroll
    for (int mt = 0; mt < 4; ++mt)
      af[mt] = *(const s16x8*)&As[wm * 64 + mt * 16 + c][q * 8];
#pragma unroll
    for (int nt = 0; nt < 4; ++nt)
      bf[nt] = *(const s16x8*)&Bs[wn * 64 + nt * 16 + c][q * 8];
#pragma unroll
    for (int mt = 0; mt < 4; ++mt)
#pragma unroll
      for (int nt = 0; nt < 4; ++nt)
        acc[mt][nt] = MFMA16(af[mt], bf[nt], acc[mt][nt], 0, 0, 0);
  }

#pragma unroll
  for (int mt = 0; mt < 4; ++mt)
#pragma unroll
    for (int nt = 0; nt < 4; ++nt)
#pragma unroll
      for (int r = 0; r < 4; ++r) {
        const int gm = m0 + wm * 64 + mt * 16 + q * 4 + r;
        const int gn = n0 + wn * 64 + nt * 16 + c;
        const float v = acc[mt][nt][r];
        const int bb = gm >> 11, s = gm & (SEQ - 1);
        if (mode == 0) {
          const int z = gn >> 9, gn5 = gn & 511;
          const int h = gn5 >> 6, d = gn5 & 63;
          if (z == 0) {
            const size_t base = (((size_t)bb * NH + h) * SEQ + s) * DK + d;
            qu[base] = f2bf((v + ubv[gn5]) * QSCALE);
            qv[base] = f2bf((v + vbv[gn5]) * QSCALE);
          } else if (z == 1) {
            kb[(((size_t)bb * NH + h) * SEQ + s) * DK + d] = f2bf(v);
          } else {
            const int s_il = (s & ~31) | pinv(s & 31);
            vt[(((size_t)bb * NH + h) * DK + d) * SEQ + s_il] = f2bf(v);
          }
        } else if (mode == 3) {
          const int h = gn >> 6, d = gn & 63;
          qu[((size_t)h * PPAD + POFF + gm) * DK + d] = f2bf(v);
        } else {
          of[(size_t)gm * DM + gn] = v;
        }
      }
}

// ---- band GEMM helper: G = Qrow-block x P[tile*16 .. +15]  (P from L2) ----
static __device__ __forceinline__ f32x4 band_gemm(const ushortT* pb, int tile,
                                                  int c, int q, s16x8 a0, s16x8 a1) {
  const ushortT* pc = pb + (ptrdiff_t)(tile * 16 + c) * DK + q * 8;
  f32x4 G = {0.f, 0.f, 0.f, 0.f};
  G = MFMA16(a0, *(const s16x8*)pc, G, 0, 0, 0);
  G = MFMA16(a1, *(const s16x8*)(pc + 32), G, 0, 0, 0);
  return G;
}

// shear-transpose band triple -> per-Q-row slots (diagonal select via kcol)
static __device__ __forceinline__ void write_band(float (*E)[PSTR], int c, int m_w,
                                                  f32x4 b0, f32x4 b1, f32x4 b2) {
  const f32x4 bb[3] = {b0, b1, b2};
#pragma unroll
  for (int t = 0; t < 3; ++t)
#pragma unroll
    for (int r = 0; r < 4; ++r) {
      const int kcol = t * 16 + c + (m_w + r) - 15;
      if (kcol >= 0 && kcol < 32) E[m_w + r][pinv(kcol)] = bb[t][r];
    }
}

// ---- MFMA flash relative attention: LDS-staged K/V, TRANSPOSED scores,
// band SOFTWARE-PIPELINED one iteration ahead (double-buffered E1):
// iteration n combines with bands written during iteration n-1, so neither
// the P global-load latency nor the E-band LDS shear round trip sits on the
// exp/PV critical chain. Phase-B (diagonal, 2/64 iters) stays synchronous.
// NOTE (r8/r9 lesson): do NOT hoist the pipelined band's P loads into
// registers at iteration top -- the exec-masked long-lived p10..p21 regs
// flip the allocator into the spill regime (WRITE_SIZE 8->53 MB, +100 us).
// Pointer-fed band_gemm keeps live ranges short; this exact text measured
// attn 211-228 us / 358.8 us total with WRITE_SIZE 8192 KB.
__global__ __launch_bounds__(256, 3)
void attn_mfma(const ushortT* __restrict__ Qu, const ushortT* __restrict__ Qv,
               const ushortT* __restrict__ Kb, const ushortT* __restrict__ Vt,
               const ushortT* __restrict__ Pp, ushortT* __restrict__ ctxb) {
  const int n = blockIdx.x;
  const int xcd = n & 7, idx = n >> 3;      // XCD x serves h=x (L2 locality)
  const int b = idx >> 5, iblk = idx & 31;
  const int h = xcd, bh = b * 8 + h;
  const int tid = threadIdx.x;
  const int w = tid >> 6, lane = tid & 63;
  const int c = lane & 15, q = lane >> 4;
  const int i0 = iblk * 64;
  const int iw = i0 + w * 16;

  __shared__ ushortT Ks[64][KSTR];
  __shared__ ushortT Vs[64][KSTR];
  __shared__ float E1[4][2][16][PSTR];  // double-buffered pipelined band
  __shared__ float E2[4][16][PSTR];     // region-2 band (phase B only, sync)
  __shared__ float Lb[4][16];

  const ushortT* Qub = Qu + ((size_t)bh * SEQ + iw) * DK;
  const ushortT* Qvb = Qv + ((size_t)bh * SEQ + iw) * DK;
  const ushortT* Kbh = Kb + (size_t)bh * SEQ * DK;
  const ushortT* Vbh = Vt + (size_t)bh * DK * SEQ;
  const ushortT* Ph  = Pp + ((size_t)h * PPAD + POFF) * DK;

  const s16x8 qu0 = *(const s16x8*)(Qub + (size_t)c * DK + q * 8);
  const s16x8 qu1 = *(const s16x8*)(Qub + (size_t)c * DK + 32 + q * 8);
  const s16x8 qv0 = *(const s16x8*)(Qvb + (size_t)c * DK + q * 8);
  const s16x8 qv1 = *(const s16x8*)(Qvb + (size_t)c * DK + 32 + q * 8);
  const s16x8 qw0 = *(const s16x8*)(Qvb + (size_t)(c + 1) * DK + q * 8);
  const s16x8 qw1 = *(const s16x8*)(Qvb + (size_t)(c + 1) * DK + 32 + q * 8);

  // per-slot j-local offsets: pi(q*8+jj)
  int joff[8];
#pragma unroll
  for (int jj = 0; jj < 8; ++jj)
    joff[jj] = (jj < 4) ? (4 * q + jj) : (16 + 4 * q + (jj - 4));

  f32x4 O[4];
#pragma unroll
  for (int r = 0; r < 4; ++r) O[r] = (f32x4){0.f, 0.f, 0.f, 0.f};
  float lrow = 0.f;
  f32x4 e2c = (f32x4){0.f, 0.f, 0.f, 0.f};
  bool hv1 = false, hv2 = false;
  const int jt = iw & ~31;
  const int m_w = q * 4;

  // ---- prologue: stage chunk 0 ----
  {
    const ushortT* gk = Kbh;
    uint4 k0v = *(const uint4*)(gk + tid * 8);
    uint4 k1v = *(const uint4*)(gk + 2048 + tid * 8);
    const ushortT* gv = Vbh + (size_t)(tid >> 2) * SEQ + (tid & 3) * 16;
    uint4 v0v = *(const uint4*)gv;
    uint4 v1v = *(const uint4*)(gv + 8);
    *(uint4*)&Ks[tid >> 3][(tid & 7) * 8] = k0v;
    *(uint4*)&Ks[32 + (tid >> 3)][(tid & 7) * 8] = k1v;
    *(uint4*)&Vs[tid >> 2][(tid & 3) * 16] = v0v;
    *(uint4*)&Vs[tid >> 2][(tid & 3) * 16 + 8] = v1v;
  }
  __syncthreads();

  // ---- prologue: band(0) (phase A iff jt > 0; else n=0 is phase B, sync)
  if (jt > 0) {
    const ushortT* pb1 = Ph + (ptrdiff_t)(0 - iw + SEQ - 16) * DK;
    f32x4 b0 = band_gemm(pb1, 0, c, q, qv0, qv1);
    f32x4 b1 = band_gemm(pb1, 1, c, q, qv0, qv1);
    e2c = band_gemm(pb1, 2, c, q, qv0, qv1);
    hv1 = true;
    write_band(E1[w][0], c, m_w, b0, b1, e2c);
  }

#define PV_FROM(pr, jl)                                                       \
  {                                                                           \
    lrow += pr[0] + pr[1] + pr[2] + pr[3] + pr[4] + pr[5] + pr[6] + pr[7];    \
    const s16x8 pa = pack8(pr);                                               \
    _Pragma("unroll")                                                         \
    for (int dt = 0; dt < 4; ++dt) {                                          \
      const s16x8 vb = *(const s16x8*)&Vs[dt * 16 + c][(jl) + q * 8];         \
      O[dt] = MFMA16(pa, vb, O[dt], 0, 0, 0);                                 \
    }                                                                         \
  }

  for (int ch = 0; ch < 32; ++ch) {
    const bool more = (ch + 1) < 32;
    uint4 k0v, k1v, v0v, v1v;
    if (more) {  // prefetch next chunk into registers (overlaps compute)
      const ushortT* gk = Kbh + (size_t)(ch + 1) * 64 * DK;
      k0v = *(const uint4*)(gk + tid * 8);
      k1v = *(const uint4*)(gk + 2048 + tid * 8);
      const ushortT* gv = Vbh + (size_t)(tid >> 2) * SEQ + (ch + 1) * 64 + (tid & 3) * 16;
      v0v = *(const uint4*)gv;
      v1v = *(const uint4*)(gv + 8);
    }
#pragma unroll
    for (int t = 0; t < 2; ++t) {
      const int nn = ch * 2 + t;
      const int j0 = nn * 32;
      const int jl = t * 32;
      const int drel = j0 - iw;
      const bool curB = (j0 >= jt) && (j0 < jt + 64);

      // transposed content scores: S^T[j=q*4+r (+16)][i=c], K from LDS
      f32x4 S0 = {0.f, 0.f, 0.f, 0.f}, S1 = {0.f, 0.f, 0.f, 0.f};
      {
        const ushortT* ka = &Ks[jl + c][q * 8];
        S0 = MFMA16(*(const s16x8*)ka, qu0, S0, 0, 0, 0);
        S0 = MFMA16(*(const s16x8*)(ka + 32), qu1, S0, 0, 0, 0);
        const ushortT* ka2 = &Ks[jl + 16 + c][q * 8];
        S1 = MFMA16(*(const s16x8*)ka2, qu0, S1, 0, 0, 0);
        S1 = MFMA16(*(const s16x8*)(ka2 + 32), qu1, S1, 0, 0, 0);
      }

      if (curB) {  // ---- synchronous two-region band at the diagonal ----
        {
          const ushortT* pb1 = Ph + (ptrdiff_t)(drel + SEQ - 16) * DK;
          f32x4 b0 = band_gemm(pb1, 0, c, q, qv0, qv1);
          f32x4 b1 = band_gemm(pb1, 1, c, q, qv0, qv1);
          f32x4 b2 = band_gemm(pb1, 2, c, q, qv0, qv1);
          write_band(E1[w][nn & 1], c, m_w, b0, b1, b2);
        }
        {
          const ushortT* pb2 = Ph + (ptrdiff_t)(drel - 17) * DK;
          f32x4 b0 = band_gemm(pb2, 0, c, q, qw0, qw1);
          f32x4 b1 = band_gemm(pb2, 1, c, q, qw0, qw1);
          f32x4 b2 = band_gemm(pb2, 2, c, q, qw0, qw1);
          write_band(E2[w], c, m_w, b0, b1, b2);
        }
        const float* e1r = &E1[w][nn & 1][c][q * 8];
        const float* e2r = &E2[w][c][q * 8];
        float4 aA = *(const float4*)e1r, aB = *(const float4*)(e1r + 4);
        float4 bA = *(const float4*)e2r, bB = *(const float4*)(e2r + 4);
        float f1[8] = {aA.x, aA.y, aA.z, aA.w, aB.x, aB.y, aB.z, aB.w};
        float f2[8] = {bA.x, bA.y, bA.z, bA.w, bB.x, bB.y, bB.z, bB.w};
        float sv[8] = {S0[0], S0[1], S0[2], S0[3], S1[0], S1[1], S1[2], S1[3]};
        float pr[8];
#pragma unroll
        for (int jj = 0; jj < 8; ++jj) {
          const int dlt = drel + joff[jj] - c;
          const float g = (dlt <= 0) ? f1[jj] : ((dlt == 1) ? 0.0f : f2[jj]);
          pr[jj] = fexp2(sv[jj] + g);
        }
        PV_FROM(pr, jl)
      } else {     // ---- common path: band was pipelined last iteration ----
        const float* e1r = &E1[w][nn & 1][c][q * 8];
        float4 fA = *(const float4*)e1r, fB = *(const float4*)(e1r + 4);
        float pr[8] = {fexp2(S0[0] + fA.x), fexp2(S0[1] + fA.y),
                       fexp2(S0[2] + fA.z), fexp2(S0[3] + fA.w),
                       fexp2(S1[0] + fB.x), fexp2(S1[1] + fB.y),
                       fexp2(S1[2] + fB.z), fexp2(S1[3] + fB.w)};
        PV_FROM(pr, jl)
      }

      // ---- pipeline band(n+1) into E1[(n+1)&1] (skip if next is phase B)
      if (nn + 1 < 64) {
        const int j0n = j0 + 32;
        const bool nxtB = (j0n >= jt) && (j0n < jt + 64);
        if (!nxtB) {
          const int dreln = j0n - iw;
          if (j0n < jt) {        // next is phase A (region 1, qv)
            const ushortT* pb1 = Ph + (ptrdiff_t)(dreln + SEQ - 16) * DK;
            f32x4 b0;
            if (hv1) b0 = e2c;
            else { b0 = band_gemm(pb1, 0, c, q, qv0, qv1); hv1 = true; }
            f32x4 b1 = band_gemm(pb1, 1, c, q, qv0, qv1);
            e2c = band_gemm(pb1, 2, c, q, qv0, qv1);
            write_band(E1[w][(nn + 1) & 1], c, m_w, b0, b1, e2c);
          } else {               // next is phase C (region 2, qw)
            const ushortT* pb2 = Ph + (ptrdiff_t)(dreln - 17) * DK;
            f32x4 b0;
            if (hv2) b0 = e2c;
            else { b0 = band_gemm(pb2, 0, c, q, qw0, qw1); hv2 = true; }
            f32x4 b1 = band_gemm(pb2, 1, c, q, qw0, qw1);
            e2c = band_gemm(pb2, 2, c, q, qw0, qw1);
            write_band(E1[w][(nn + 1) & 1], c, m_w, b0, b1, e2c);
          }
        }
      }
    }
    __syncthreads();                     // all waves done reading Ks/Vs
    if (more) {
      *(uint4*)&Ks[tid >> 3][(tid & 7) * 8] = k0v;
      *(uint4*)&Ks[32 + (tid >> 3)][(tid & 7) * 8] = k1v;
      *(uint4*)&Vs[tid >> 2][(tid & 3) * 16] = v0v;
      *(uint4*)&Vs[tid >> 2][(tid & 3) * 16 + 8] = v1v;
    }
    __syncthreads();                     // staging visible
  }

  // ---- epilogue (rows exclusive to this wave) ----
  lrow += __shfl_xor(lrow, 16);
  lrow += __shfl_xor(lrow, 32);
  if (q == 0) Lb[w][c] = lrow;
  float inv[4];
#pragma unroll
  for (int r = 0; r < 4; ++r) inv[r] = 1.0f / Lb[w][q * 4 + r];
#pragma unroll
  for (int dt = 0; dt < 4; ++dt)
#pragma unroll
    for (int r = 0; r < 4; ++r) {
      const int i = iw + q * 4 + r;
      ctxb[((size_t)b * SEQ + i) * DM + h * DK + dt * 16 + c] = f2bf(O[dt][r] * inv[r]);
    }
}

extern "C" void kernel_launch(void* const* d_in, const int* in_sizes, int n_in,
                              void* d_out, int out_size, void* d_ws, size_t ws_size,
                              hipStream_t stream) {
  (void)in_sizes; (void)n_in; (void)out_size; (void)ws_size;
  const float* X   = (const float*)d_in[0];
  const float* PE  = (const float*)d_in[1];
  const float* Wq  = (const float*)d_in[2];
  const float* Wk  = (const float*)d_in[3];
  const float* Wv  = (const float*)d_in[4];
  const float* Wo  = (const float*)d_in[5];
  const float* Wp  = (const float*)d_in[6];
  const float* ubv = (const float*)d_in[7];
  const float* vbv = (const float*)d_in[8];

  const size_t NX = (size_t)4 * SEQ * DM;   // 4 Mi
  const size_t NP = (size_t)SEQ * DM;       // 1 Mi
  const size_t NW = (size_t)DM * DM;        // 256 Ki
  ushortT* Xb  = (ushortT*)d_ws;
  ushortT* PEb = Xb + NX;
  ushortT* Wt  = PEb + NP;                  // [Wq^T;Wk^T;Wv^T;Wp^T;Wo^T] bf16
  ushortT* qu  = Wt + 5 * NW;
  ushortT* qv  = qu + NX;
  ushortT* kb  = qv + NX;                   // qw overread from qv lands here: safe
  ushortT* vt  = kb + NX;
  ushortT* pp  = vt + NX;                   // NH*PPAD*DK
  ushortT* ctx = pp + (size_t)NH * PPAD * DK;
  float* outp = (float*)d_out;

  hipLaunchKernelGGL(cast_in, dim3((NX + NP) / 4 / 256), dim3(256), 0, stream, X, PE, Xb, PEb);
  hipLaunchKernelGGL(transpose_w, dim3(16, 16, 5), dim3(32, 8), 0, stream, Wq, Wk, Wv, Wp, Wo, Wt);
  dim3 blk(256);
  hipLaunchKernelGGL(gemm_mfma, dim3(64, 12), blk, 0, stream, Xb, Wt, ubv, vbv,
                     qu, qv, kb, vt, (float*)nullptr, 0);
  hipLaunchKernelGGL(gemm_mfma, dim3(16, 4), blk, 0, stream, PEb, Wt + 3 * NW, ubv, vbv,
                     pp, (ushortT*)nullptr, (ushortT*)nullptr, (ushortT*)nullptr, (float*)nullptr, 3);
  hipLaunchKernelGGL(attn_mfma, dim3(1024), blk, 0, stream, qu, qv, kb, vt, pp, ctx);
  hipLaunchKernelGGL(gemm_mfma, dim3(64, 4), blk, 0, stream, ctx, Wt + 4 * NW, ubv, vbv,
                     (ushortT*)nullptr, (ushortT*)nullptr, (ushortT*)nullptr, (ushortT*)nullptr, outp, 4);
}